// Round 6
// baseline (398.458 us; speedup 1.0000x reference)
//
#include <hip/hip_runtime.h>
#include <math.h>

#define B_ 64
#define S_ 64
#define U_ 16
#define EMB_ 10
#define D_ 34
#define DD_ 3
#define FF_ 4
#define NL_ 4

// ---------------------------------------------------------------------------
// Kernel A: embedding + pos-encoding quirk + 4 post-norm encoder layers +
// final LN + projection to memory[B,S,3] (stored in d_ws).
// One block per batch element, 512 threads. (unchanged from R5)
// ---------------------------------------------------------------------------
__global__ __launch_bounds__(512) void enc_kernel(
    const float* __restrict__ src, const float* __restrict__ wemb,
    const float* __restrict__ semb,
    const float* __restrict__ qkv_w, const float* __restrict__ qkv_b,
    const float* __restrict__ out_w, const float* __restrict__ out_b,
    const float* __restrict__ ln1_w, const float* __restrict__ ln1_b,
    const float* __restrict__ lin1_w, const float* __restrict__ lin1_b,
    const float* __restrict__ lin2_w, const float* __restrict__ lin2_b,
    const float* __restrict__ ln2_w, const float* __restrict__ ln2_b,
    const float* __restrict__ norm_w, const float* __restrict__ norm_b,
    const float* __restrict__ eo_w, const float* __restrict__ eo_b,
    float* __restrict__ mem, float* __restrict__ out)
{
    const int b = blockIdx.x;
    const int tid = threadIdx.x;

    __shared__ float xs[S_][D_ + 1];
    __shared__ float qs[S_][D_];
    __shared__ float ks[S_][D_];
    __shared__ float vs[S_][D_];
    __shared__ float att[S_][D_];
    __shared__ float ffh[S_][FF_];
    __shared__ float tmp[S_][D_ + 1];
    __shared__ float pacc[4][128][19];
    __shared__ float wq_s[3 * D_ * D_];
    __shared__ float wo_s[D_ * D_];
    __shared__ float w1_s[FF_ * D_];
    __shared__ float w2_s[D_ * FF_];
    __shared__ float bq_s[3 * D_], bo_s[D_], b1_s[FF_], b2_s[D_];
    __shared__ float l1w_s[D_], l1b_s[D_], l2w_s[D_], l2b_s[D_];

    const float negln = -logf(10000.0f) / (float)D_;
    #pragma unroll
    for (int rep = 0; rep < 5; ++rep) {
        int idx = tid + rep * 512;
        if (idx < S_ * D_) {
            int pos = idx / D_, d = idx % D_;
            float v;
            if (d < U_ - 2) {
                v = src[(b * S_ + pos) * U_ + d];
            } else if (d < U_ - 2 + EMB_) {
                int wi = (int)src[(b * S_ + pos) * U_ + (U_ - 2)];
                v = wemb[wi * EMB_ + (d - (U_ - 2))];
            } else {
                int si = (int)src[(b * S_ + pos) * U_ + (U_ - 1)];
                v = semb[si * EMB_ + (d - (U_ - 2 + EMB_))];
            }
            int k = d >> 1;
            float div = expf((float)(2 * k) * negln);
            float ang = (float)b * div;
            v += (d & 1) ? cosf(ang) : sinf(ang);
            xs[pos][d] = v;
        }
    }
    __syncthreads();

    const float rs17 = 0.24253562503633297f;

    for (int l = 0; l < NL_; ++l) {
        for (int t = tid; t < 3 * D_ * D_; t += 512) wq_s[t] = qkv_w[l * 3 * D_ * D_ + t];
        for (int t = tid; t < D_ * D_; t += 512)     wo_s[t] = out_w[l * D_ * D_ + t];
        for (int t = tid; t < FF_ * D_; t += 512)    w1_s[t] = lin1_w[l * FF_ * D_ + t];
        for (int t = tid; t < D_ * FF_; t += 512)    w2_s[t] = lin2_w[l * D_ * FF_ + t];
        for (int t = tid; t < 3 * D_ + 6 * D_ + FF_; t += 512) {
            if      (t < 3 * D_)          bq_s[t]            = qkv_b[l * 3 * D_ + t];
            else if (t < 3 * D_ + D_)     bo_s[t - 3 * D_]   = out_b[l * D_ + (t - 3 * D_)];
            else if (t < 3 * D_ + 2 * D_) l1w_s[t - 4 * D_]  = ln1_w[l * D_ + (t - 4 * D_)];
            else if (t < 3 * D_ + 3 * D_) l1b_s[t - 5 * D_]  = ln1_b[l * D_ + (t - 5 * D_)];
            else if (t < 3 * D_ + 4 * D_) l2w_s[t - 6 * D_]  = ln2_w[l * D_ + (t - 6 * D_)];
            else if (t < 3 * D_ + 5 * D_) l2b_s[t - 7 * D_]  = ln2_b[l * D_ + (t - 7 * D_)];
            else if (t < 3 * D_ + 6 * D_) b2_s[t - 8 * D_]   = lin2_b[l * D_ + (t - 8 * D_)];
            else                          b1_s[t - 9 * D_]   = lin1_b[l * FF_ + (t - 9 * D_)];
        }
        __syncthreads();

        #pragma unroll 2
        for (int rep = 0; rep < 13; ++rep) {
            int idx = tid + rep * 512;
            if (idx < S_ * 3 * D_) {
                int pos = idx / (3 * D_), r = idx % (3 * D_);
                const float* wrow = wq_s + r * D_;
                float aE = bq_s[r], aO = 0.f;
                #pragma unroll
                for (int d = 0; d < D_; d += 2) {
                    aE += xs[pos][d] * wrow[d];
                    aO += xs[pos][d + 1] * wrow[d + 1];
                }
                float acc = aE + aO;
                if (r < D_)          qs[pos][r] = acc;
                else if (r < 2 * D_) ks[pos][r - D_] = acc;
                else                 vs[pos][r - 2 * D_] = acc;
            }
        }
        __syncthreads();

        {
            int c = tid >> 7, hq = tid & 127;
            int h = hq >> 6, qi = hq & 63;
            int off = h * 17;
            float qv[17], acc[17];
            #pragma unroll
            for (int d = 0; d < 17; ++d) { qv[d] = qs[qi][off + d]; acc[d] = 0.f; }
            float ssum = 0.f;
            int j0 = c * 16;
            #pragma unroll 2
            for (int jj = 0; jj < 16; ++jj) {
                int j = j0 + jj;
                float sE = 0.f, sO = 0.f;
                #pragma unroll
                for (int d = 0; d < 16; d += 2) {
                    sE += qv[d] * ks[j][off + d];
                    sO += qv[d + 1] * ks[j][off + d + 1];
                }
                float sc = sE + sO + qv[16] * ks[j][off + 16];
                float e = __expf(sc * rs17);
                ssum += e;
                #pragma unroll
                for (int d = 0; d < 17; ++d) acc[d] += e * vs[j][off + d];
            }
            #pragma unroll
            for (int d = 0; d < 17; ++d) pacc[c][hq][d] = acc[d];
            pacc[c][hq][17] = ssum;
        }
        __syncthreads();

        if (tid < 128) {
            int h = tid >> 6, qi = tid & 63;
            int off = h * 17;
            float ssum = pacc[0][tid][17] + pacc[1][tid][17] +
                         pacc[2][tid][17] + pacc[3][tid][17];
            float inv = 1.f / ssum;
            #pragma unroll
            for (int d = 0; d < 17; ++d)
                att[qi][off + d] = (pacc[0][tid][d] + pacc[1][tid][d] +
                                    pacc[2][tid][d] + pacc[3][tid][d]) * inv;
        }
        __syncthreads();

        #pragma unroll 2
        for (int rep = 0; rep < 5; ++rep) {
            int idx = tid + rep * 512;
            if (idx < S_ * D_) {
                int pos = idx / D_, d = idx % D_;
                const float* wrow = wo_s + d * D_;
                float aE = bo_s[d], aO = 0.f;
                #pragma unroll
                for (int e = 0; e < D_; e += 2) {
                    aE += att[pos][e] * wrow[e];
                    aO += att[pos][e + 1] * wrow[e + 1];
                }
                tmp[pos][d] = xs[pos][d] + aE + aO;
            }
        }
        __syncthreads();

        if (tid < S_) {
            int row = tid;
            float sA = 0.f, sB = 0.f;
            #pragma unroll
            for (int d = 0; d < D_; d += 2) { sA += tmp[row][d]; sB += tmp[row][d + 1]; }
            float mu = (sA + sB) * (1.0f / D_);
            float vA = 0.f, vB = 0.f;
            #pragma unroll
            for (int d = 0; d < D_; d += 2) {
                float t0 = tmp[row][d] - mu;     vA += t0 * t0;
                float t1 = tmp[row][d + 1] - mu; vB += t1 * t1;
            }
            float rstd = rsqrtf((vA + vB) * (1.0f / D_) + 1e-5f);
            #pragma unroll
            for (int d = 0; d < D_; ++d)
                xs[row][d] = (tmp[row][d] - mu) * rstd * l1w_s[d] + l1b_s[d];
        }
        __syncthreads();

        if (tid < 256) {
            int pos = tid >> 2, f = tid & 3;
            const float* wrow = w1_s + f * D_;
            float aE = b1_s[f], aO = 0.f;
            #pragma unroll
            for (int d = 0; d < D_; d += 2) {
                aE += xs[pos][d] * wrow[d];
                aO += xs[pos][d + 1] * wrow[d + 1];
            }
            ffh[pos][f] = fmaxf(aE + aO, 0.f);
        }
        __syncthreads();

        #pragma unroll 2
        for (int rep = 0; rep < 5; ++rep) {
            int idx = tid + rep * 512;
            if (idx < S_ * D_) {
                int pos = idx / D_, d = idx % D_;
                const float* wrow = w2_s + d * FF_;
                float acc = b2_s[d] + ffh[pos][0] * wrow[0] + ffh[pos][1] * wrow[1] +
                            ffh[pos][2] * wrow[2] + ffh[pos][3] * wrow[3];
                tmp[pos][d] = xs[pos][d] + acc;
            }
        }
        __syncthreads();

        if (tid < S_) {
            int row = tid;
            float sA = 0.f, sB = 0.f;
            #pragma unroll
            for (int d = 0; d < D_; d += 2) { sA += tmp[row][d]; sB += tmp[row][d + 1]; }
            float mu = (sA + sB) * (1.0f / D_);
            float vA = 0.f, vB = 0.f;
            #pragma unroll
            for (int d = 0; d < D_; d += 2) {
                float t0 = tmp[row][d] - mu;     vA += t0 * t0;
                float t1 = tmp[row][d + 1] - mu; vB += t1 * t1;
            }
            float rstd = rsqrtf((vA + vB) * (1.0f / D_) + 1e-5f);
            #pragma unroll
            for (int d = 0; d < D_; ++d)
                xs[row][d] = (tmp[row][d] - mu) * rstd * l2w_s[d] + l2b_s[d];
        }
        __syncthreads();
    }

    if (tid < S_) {
        int row = tid;
        float sA = 0.f, sB = 0.f;
        #pragma unroll
        for (int d = 0; d < D_; d += 2) { sA += xs[row][d]; sB += xs[row][d + 1]; }
        float mu = (sA + sB) * (1.0f / D_);
        float vA = 0.f, vB = 0.f;
        #pragma unroll
        for (int d = 0; d < D_; d += 2) {
            float t0 = xs[row][d] - mu;     vA += t0 * t0;
            float t1 = xs[row][d + 1] - mu; vB += t1 * t1;
        }
        float rstd = rsqrtf((vA + vB) * (1.0f / D_) + 1e-5f);
        #pragma unroll
        for (int d = 0; d < D_; ++d)
            xs[row][d] = (xs[row][d] - mu) * rstd * norm_w[d] + norm_b[d];
    }
    __syncthreads();

    if (tid < S_ * DD_) {
        int pos = tid / DD_, r = tid % DD_;
        const float* wrow = eo_w + r * D_;
        float aE = eo_b[r], aO = 0.f;
        #pragma unroll
        for (int d = 0; d < D_; d += 2) {
            aE += xs[pos][d] * wrow[d];
            aO += xs[pos][d + 1] * wrow[d + 1];
        }
        mem[(b * S_ + pos) * DD_ + r] = aE + aO;
    }

    if (tid < S_) {
        out[(b * S_ + tid) * 5 + 3] = src[(b * S_ + tid) * U_ + (U_ - 2)];
        out[(b * S_ + tid) * 5 + 4] = src[(b * S_ + tid) * U_ + (U_ - 1)];
    }
}

// ---------------------------------------------------------------------------
// Kernel B: incremental autoregressive decoder — chain-shortened.
//  * out-projections folded into the V caches (Wso·Wv at init; Wco·cv at init)
//  * softmax normalization dropped via LN scale-invariance (z = (y+B)*es + ev)
//  * exp2 with 1/sqrt3*log2e pre-folded into score weights
//  * causal mask = fma accumulator init (computed once per step)
//  * ln3 via E[z^2]-mu^2 (sum and sumsq in parallel)
//  * ALL weights pinned to VGPRs before the loop -> zero loads on the chain
// ---------------------------------------------------------------------------
#define PIN(x) asm volatile("" : "+v"(x))

template <int CTRL>
__device__ __forceinline__ float dpp_add(float v) {
    int t = __builtin_amdgcn_update_dpp(0, __float_as_int(v), CTRL, 0xf, 0xf, true);
    return v + __int_as_float(t);
}

__device__ __forceinline__ float wave_sum_l63(float v) {
    v = dpp_add<0x111>(v);
    v = dpp_add<0x112>(v);
    v = dpp_add<0x114>(v);
    v = dpp_add<0x118>(v);
    v = dpp_add<0x142>(v);
    v = dpp_add<0x143>(v);
    return v;
}

__device__ __forceinline__ float bcast63(float v) {
    return __int_as_float(__builtin_amdgcn_readlane(__float_as_int(v), 63));
}

// LayerNorm(3) via E[z^2]-mu^2; input scale-invariant (scale > 0)
__device__ __forceinline__ void ln3e(float z0, float z1, float z2,
                                     float w0, float w1, float w2,
                                     float b0, float b1, float b2,
                                     float& o0, float& o1, float& o2) {
    float s1 = (z0 + z1) + z2;
    float s2 = fmaf(z0, z0, fmaf(z1, z1, z2 * z2));
    float mu = s1 * (1.0f / 3.0f);
    float vpe = fmaf(s2, (1.0f / 3.0f), fmaf(-mu, mu, 1e-5f));
    float rstd = __builtin_amdgcn_rsqf(vpe);
    o0 = fmaf(z0 - mu, rstd * w0, b0);
    o1 = fmaf(z1 - mu, rstd * w1, b1);
    o2 = fmaf(z2 - mu, rstd * w2, b2);
}

__global__ __launch_bounds__(64, 1) void dec_kernel(
    const float* __restrict__ mem,
    const float* __restrict__ sa_qkv_w, const float* __restrict__ sa_qkv_b,
    const float* __restrict__ sa_out_w, const float* __restrict__ sa_out_b,
    const float* __restrict__ gln1_w, const float* __restrict__ gln1_b,
    const float* __restrict__ ca_qkv_w, const float* __restrict__ ca_qkv_b,
    const float* __restrict__ ca_out_w, const float* __restrict__ ca_out_b,
    const float* __restrict__ gln2_w, const float* __restrict__ gln2_b,
    const float* __restrict__ l1_w, const float* __restrict__ l1_b,
    const float* __restrict__ l2_w, const float* __restrict__ l2_b,
    const float* __restrict__ gln3_w, const float* __restrict__ gln3_b,
    float* __restrict__ out)
{
    const int b = blockIdx.x;
    const int lane = threadIdx.x;
    const float LOG2E = 1.4426950408889634f;
    const float rs3 = 0.5773502691896258f;
    const float QS = rs3 * LOG2E;   // folded into score-producing weights

    // ---- persistent weights (all pinned below)
    float Wqp[NL_][3][3], Bqp[NL_][3];      // q-proj, pre-scaled by QS
    float Wk [NL_][3][3], Bk [NL_][3];      // k-proj
    float WVp[NL_][3][3], bvp[NL_][3];      // (Wso*Wv), Wso*bv  -> v' cache
    float Bso[NL_][3];
    float Wcq[NL_][3][3], Bcq[NL_][3];      // CA q-proj (score scale in ck)
    float Bco[NL_][3];
    float N1w[NL_][3], N1b[NL_][3];
    float N2w[NL_][3], N2b[NL_][3];
    float F1w[NL_][4][3], F1b[NL_][4];
    float F2w[NL_][3][4], F2b[NL_][3];
    float N3w[NL_][3], N3b[NL_][3];

    #pragma unroll
    for (int l = 0; l < NL_; ++l) {
        #pragma unroll
        for (int r = 0; r < 3; ++r) {
            Bqp[l][r] = sa_qkv_b[l * 9 + r] * QS;
            Bk [l][r] = sa_qkv_b[l * 9 + 3 + r];
            #pragma unroll
            for (int c = 0; c < 3; ++c) {
                Wqp[l][r][c] = sa_qkv_w[l * 27 + r * 3 + c] * QS;
                Wk [l][r][c] = sa_qkv_w[l * 27 + (3 + r) * 3 + c];
            }
            // WVp = Wso * Wv ; bvp = Wso * bv
            float a0 = 0.f, a1 = 0.f, a2 = 0.f, ab = 0.f;
            #pragma unroll
            for (int t = 0; t < 3; ++t) {
                float wso = sa_out_w[l * 9 + r * 3 + t];
                a0 += wso * sa_qkv_w[l * 27 + (6 + t) * 3 + 0];
                a1 += wso * sa_qkv_w[l * 27 + (6 + t) * 3 + 1];
                a2 += wso * sa_qkv_w[l * 27 + (6 + t) * 3 + 2];
                ab += wso * sa_qkv_b[l * 9 + 6 + t];
            }
            WVp[l][r][0] = a0; WVp[l][r][1] = a1; WVp[l][r][2] = a2;
            bvp[l][r] = ab;
            Bso[l][r] = sa_out_b[l * 3 + r];
            Bcq[l][r] = ca_qkv_b[l * 9 + r];
            Bco[l][r] = ca_out_b[l * 3 + r];
            #pragma unroll
            for (int c = 0; c < 3; ++c) Wcq[l][r][c] = ca_qkv_w[l * 27 + r * 3 + c];
            N1w[l][r] = gln1_w[l * 3 + r];  N1b[l][r] = gln1_b[l * 3 + r];
            N2w[l][r] = gln2_w[l * 3 + r];  N2b[l][r] = gln2_b[l * 3 + r];
            N3w[l][r] = gln3_w[l * 3 + r];  N3b[l][r] = gln3_b[l * 3 + r];
            F2b[l][r] = l2_b[l * 3 + r];
            #pragma unroll
            for (int c = 0; c < 4; ++c) F2w[l][r][c] = l2_w[l * 12 + r * 4 + c];
        }
        #pragma unroll
        for (int f = 0; f < 4; ++f) {
            F1b[l][f] = l1_b[l * 4 + f];
            #pragma unroll
            for (int c = 0; c < 3; ++c) F1w[l][f][c] = l1_w[l * 12 + f * 3 + c];
        }
    }

    // ---- cross-attn caches per lane: ck scaled by QS, cv' = Wco*cv
    float m0 = mem[(b * S_ + lane) * DD_ + 0];
    float m1 = mem[(b * S_ + lane) * DD_ + 1];
    float m2 = mem[(b * S_ + lane) * DD_ + 2];

    float ck[NL_][3], cvp[NL_][3];
    #pragma unroll
    for (int l = 0; l < NL_; ++l) {
        float cvt[3];
        #pragma unroll
        for (int t = 0; t < 3; ++t) {
            cvt[t] = ca_qkv_w[l * 27 + (6 + t) * 3 + 0] * m0 +
                     ca_qkv_w[l * 27 + (6 + t) * 3 + 1] * m1 +
                     ca_qkv_w[l * 27 + (6 + t) * 3 + 2] * m2 + ca_qkv_b[l * 9 + 6 + t];
        }
        #pragma unroll
        for (int r = 0; r < 3; ++r) {
            float kk = ca_qkv_w[l * 27 + (3 + r) * 3 + 0] * m0 +
                       ca_qkv_w[l * 27 + (3 + r) * 3 + 1] * m1 +
                       ca_qkv_w[l * 27 + (3 + r) * 3 + 2] * m2 + ca_qkv_b[l * 9 + 3 + r];
            ck[l][r] = kk * QS;
            cvp[l][r] = ca_out_w[l * 9 + r * 3 + 0] * cvt[0] +
                        ca_out_w[l * 9 + r * 3 + 1] * cvt[1] +
                        ca_out_w[l * 9 + r * 3 + 2] * cvt[2];
        }
    }

    // ---- pin everything into VGPRs (no loads inside the i-loop)
    #pragma unroll
    for (int l = 0; l < NL_; ++l) {
        #pragma unroll
        for (int r = 0; r < 3; ++r) {
            PIN(Bqp[l][r]); PIN(Bk[l][r]); PIN(bvp[l][r]); PIN(Bso[l][r]);
            PIN(Bcq[l][r]); PIN(Bco[l][r]);
            PIN(N1w[l][r]); PIN(N1b[l][r]); PIN(N2w[l][r]); PIN(N2b[l][r]);
            PIN(N3w[l][r]); PIN(N3b[l][r]); PIN(F2b[l][r]);
            PIN(ck[l][r]); PIN(cvp[l][r]);
            #pragma unroll
            for (int c = 0; c < 3; ++c) {
                PIN(Wqp[l][r][c]); PIN(Wk[l][r][c]); PIN(WVp[l][r][c]); PIN(Wcq[l][r][c]);
            }
            #pragma unroll
            for (int c = 0; c < 4; ++c) PIN(F2w[l][r][c]);
        }
        #pragma unroll
        for (int f = 0; f < 4; ++f) {
            PIN(F1b[l][f]);
            #pragma unroll
            for (int c = 0; c < 3; ++c) PIN(F1w[l][f][c]);
        }
    }

    // self-attn cache: lane j owns position j; v' = Wso*v form
    float sk[NL_][3] = {{0.f}}, sv[NL_][3] = {{0.f}};

    if (lane < 3) out[(b * S_ + 0) * 5 + lane] = 0.f;

    float y0 = 0.f, y1 = 0.f, y2 = 0.f;

    for (int i = 0; i < S_ - 1; ++i) {
        float msa = (lane <= i) ? 0.f : -1.0e30f;   // once per step
        #pragma unroll
        for (int l = 0; l < NL_; ++l) {
            // ---- causal self-attention (q pre-scaled; v' = Wso*v)
            float q0 = fmaf(Wqp[l][0][0], y0, fmaf(Wqp[l][0][1], y1, fmaf(Wqp[l][0][2], y2, Bqp[l][0])));
            float q1 = fmaf(Wqp[l][1][0], y0, fmaf(Wqp[l][1][1], y1, fmaf(Wqp[l][1][2], y2, Bqp[l][1])));
            float q2 = fmaf(Wqp[l][2][0], y0, fmaf(Wqp[l][2][1], y1, fmaf(Wqp[l][2][2], y2, Bqp[l][2])));
            float k0 = fmaf(Wk[l][0][0], y0, fmaf(Wk[l][0][1], y1, fmaf(Wk[l][0][2], y2, Bk[l][0])));
            float k1 = fmaf(Wk[l][1][0], y0, fmaf(Wk[l][1][1], y1, fmaf(Wk[l][1][2], y2, Bk[l][1])));
            float k2 = fmaf(Wk[l][2][0], y0, fmaf(Wk[l][2][1], y1, fmaf(Wk[l][2][2], y2, Bk[l][2])));
            float v0 = fmaf(WVp[l][0][0], y0, fmaf(WVp[l][0][1], y1, fmaf(WVp[l][0][2], y2, bvp[l][0])));
            float v1 = fmaf(WVp[l][1][0], y0, fmaf(WVp[l][1][1], y1, fmaf(WVp[l][1][2], y2, bvp[l][1])));
            float v2 = fmaf(WVp[l][2][0], y0, fmaf(WVp[l][2][1], y1, fmaf(WVp[l][2][2], y2, bvp[l][2])));
            if (lane == i) {
                sk[l][0] = k0; sk[l][1] = k1; sk[l][2] = k2;
                sv[l][0] = v0; sv[l][1] = v1; sv[l][2] = v2;
            }
            float sc = fmaf(q0, sk[l][0], fmaf(q1, sk[l][1], fmaf(q2, sk[l][2], msa)));
            float e = __builtin_amdgcn_exp2f(sc);
            float es  = bcast63(wave_sum_l63(e));
            float ev0 = bcast63(wave_sum_l63(e * sv[l][0]));
            float ev1 = bcast63(wave_sum_l63(e * sv[l][1]));
            float ev2 = bcast63(wave_sum_l63(e * sv[l][2]));
            // LN scale-invariance: feed z = (y+Bso)*es + ev (unnormalized)
            float t0 = y0 + Bso[l][0], t1 = y1 + Bso[l][1], t2 = y2 + Bso[l][2];
            float z0 = fmaf(t0, es, ev0);
            float z1 = fmaf(t1, es, ev1);
            float z2 = fmaf(t2, es, ev2);
            ln3e(z0, z1, z2, N1w[l][0], N1w[l][1], N1w[l][2],
                 N1b[l][0], N1b[l][1], N1b[l][2], y0, y1, y2);

            // ---- cross-attention (score scale folded into ck; cv' = Wco*cv)
            float p0 = fmaf(Wcq[l][0][0], y0, fmaf(Wcq[l][0][1], y1, fmaf(Wcq[l][0][2], y2, Bcq[l][0])));
            float p1 = fmaf(Wcq[l][1][0], y0, fmaf(Wcq[l][1][1], y1, fmaf(Wcq[l][1][2], y2, Bcq[l][1])));
            float p2 = fmaf(Wcq[l][2][0], y0, fmaf(Wcq[l][2][1], y1, fmaf(Wcq[l][2][2], y2, Bcq[l][2])));
            float sc2 = fmaf(p0, ck[l][0], fmaf(p1, ck[l][1], p2 * ck[l][2]));
            float e2 = __builtin_amdgcn_exp2f(sc2);
            float cs  = bcast63(wave_sum_l63(e2));
            float cw0 = bcast63(wave_sum_l63(e2 * cvp[l][0]));
            float cw1 = bcast63(wave_sum_l63(e2 * cvp[l][1]));
            float cw2 = bcast63(wave_sum_l63(e2 * cvp[l][2]));
            float u0 = y0 + Bco[l][0], u1 = y1 + Bco[l][1], u2 = y2 + Bco[l][2];
            z0 = fmaf(u0, cs, cw0);
            z1 = fmaf(u1, cs, cw1);
            z2 = fmaf(u2, cs, cw2);
            ln3e(z0, z1, z2, N2w[l][0], N2w[l][1], N2w[l][2],
                 N2b[l][0], N2b[l][1], N2b[l][2], y0, y1, y2);

            // ---- feed-forward 3 -> 4 -> 3 (relu)
            float h0 = fmaxf(fmaf(F1w[l][0][0], y0, fmaf(F1w[l][0][1], y1, fmaf(F1w[l][0][2], y2, F1b[l][0]))), 0.f);
            float h1 = fmaxf(fmaf(F1w[l][1][0], y0, fmaf(F1w[l][1][1], y1, fmaf(F1w[l][1][2], y2, F1b[l][1]))), 0.f);
            float h2 = fmaxf(fmaf(F1w[l][2][0], y0, fmaf(F1w[l][2][1], y1, fmaf(F1w[l][2][2], y2, F1b[l][2]))), 0.f);
            float h3 = fmaxf(fmaf(F1w[l][3][0], y0, fmaf(F1w[l][3][1], y1, fmaf(F1w[l][3][2], y2, F1b[l][3]))), 0.f);
            float f0 = fmaf(F2w[l][0][0], h0, fmaf(F2w[l][0][1], h1, fmaf(F2w[l][0][2], h2, fmaf(F2w[l][0][3], h3, F2b[l][0]))));
            float f1 = fmaf(F2w[l][1][0], h0, fmaf(F2w[l][1][1], h1, fmaf(F2w[l][1][2], h2, fmaf(F2w[l][1][3], h3, F2b[l][1]))));
            float f2 = fmaf(F2w[l][2][0], h0, fmaf(F2w[l][2][1], h1, fmaf(F2w[l][2][2], h2, fmaf(F2w[l][2][3], h3, F2b[l][2]))));
            ln3e(y0 + f0, y1 + f1, y2 + f2, N3w[l][0], N3w[l][1], N3w[l][2],
                 N3b[l][0], N3b[l][1], N3b[l][2], y0, y1, y2);
        }
        if (lane == 0) {
            out[(b * S_ + i + 1) * 5 + 0] = y0;
            out[(b * S_ + i + 1) * 5 + 1] = y1;
            out[(b * S_ + i + 1) * 5 + 2] = y2;
        }
    }
}

// ---------------------------------------------------------------------------
extern "C" void kernel_launch(void* const* d_in, const int* in_sizes, int n_in,
                              void* d_out, int out_size, void* d_ws, size_t ws_size,
                              hipStream_t stream) {
    const float* src  = (const float*)d_in[0];
    const float* wemb = (const float*)d_in[1];
    const float* semb = (const float*)d_in[2];

    float* mem = (float*)d_ws;           // [B,S,3] scratch
    float* out = (float*)d_out;          // [B,S,5]

    enc_kernel<<<B_, 512, 0, stream>>>(
        src, wemb, semb,
        (const float*)d_in[3],  (const float*)d_in[4],
        (const float*)d_in[5],  (const float*)d_in[6],
        (const float*)d_in[7],  (const float*)d_in[8],
        (const float*)d_in[9],  (const float*)d_in[10],
        (const float*)d_in[11], (const float*)d_in[12],
        (const float*)d_in[13], (const float*)d_in[14],
        (const float*)d_in[15], (const float*)d_in[16],
        (const float*)d_in[17], (const float*)d_in[18],
        mem, out);

    dec_kernel<<<B_, 64, 0, stream>>>(
        mem,
        (const float*)d_in[19], (const float*)d_in[20],
        (const float*)d_in[21], (const float*)d_in[22],
        (const float*)d_in[23], (const float*)d_in[24],
        (const float*)d_in[25], (const float*)d_in[26],
        (const float*)d_in[27], (const float*)d_in[28],
        (const float*)d_in[29], (const float*)d_in[30],
        (const float*)d_in[31], (const float*)d_in[32],
        (const float*)d_in[33], (const float*)d_in[34],
        (const float*)d_in[35], (const float*)d_in[36],
        out);
}

// Round 7
// 367.137 us; speedup vs baseline: 1.0853x; 1.0853x over previous
//
#include <hip/hip_runtime.h>
#include <math.h>

#define B_ 64
#define S_ 64
#define U_ 16
#define EMB_ 10
#define D_ 34
#define DD_ 3
#define FF_ 4
#define NL_ 4

// ---------------------------------------------------------------------------
// Kernel A: embedding + pos-encoding quirk + 4 post-norm encoder layers +
// final LN + projection to memory[B,S,3].
// One block per batch element, 512 threads (8 waves).
// R7: r-major mappings -> weight reads are wave-uniform (LDS broadcast);
// activation reads are stride-35 (conflict-free); attention K/V stored
// head-major padded-20 for ds_read_b128 broadcast reads.
// ---------------------------------------------------------------------------
__global__ __launch_bounds__(512) void enc_kernel(
    const float* __restrict__ src, const float* __restrict__ wemb,
    const float* __restrict__ semb,
    const float* __restrict__ qkv_w, const float* __restrict__ qkv_b,
    const float* __restrict__ out_w, const float* __restrict__ out_b,
    const float* __restrict__ ln1_w, const float* __restrict__ ln1_b,
    const float* __restrict__ lin1_w, const float* __restrict__ lin1_b,
    const float* __restrict__ lin2_w, const float* __restrict__ lin2_b,
    const float* __restrict__ ln2_w, const float* __restrict__ ln2_b,
    const float* __restrict__ norm_w, const float* __restrict__ norm_b,
    const float* __restrict__ eo_w, const float* __restrict__ eo_b,
    float* __restrict__ mem, float* __restrict__ out)
{
    const int b = blockIdx.x;
    const int tid = threadIdx.x;
    const int wv_ = tid >> 6;        // wave id 0..7
    const int lane = tid & 63;

    __shared__ float xs[S_][D_ + 1];            // stride 35: lane=pos reads free
    __shared__ float tmp[S_][D_ + 1];
    __shared__ float att[S_][D_ + 1];
    __shared__ __align__(16) float qsh[2][S_][21];   // stride 21: conflict-free q reads
    __shared__ __align__(16) float ksh[2][S_][20];   // stride 20: b128-aligned rows
    __shared__ __align__(16) float vsh[2][S_][20];
    __shared__ float ffh[S_][5];
    __shared__ float pacc[4][128][19];
    // per-layer weight staging
    __shared__ float wq_s[3 * D_ * D_];
    __shared__ float wo_s[D_ * D_];
    __shared__ float w1_s[FF_ * D_];
    __shared__ float w2_s[D_ * FF_];
    __shared__ float bq_s[3 * D_], bo_s[D_], b1_s[FF_], b2_s[D_];
    __shared__ float l1w_s[D_], l1b_s[D_], l2w_s[D_], l2b_s[D_];

    // ---- embed + positional encoding (pe row b added to ALL positions)
    const float negln = -logf(10000.0f) / (float)D_;
    #pragma unroll
    for (int rep = 0; rep < 5; ++rep) {
        int idx = tid + rep * 512;
        if (idx < S_ * D_) {
            int pos = idx / D_, d = idx % D_;
            float v;
            if (d < U_ - 2) {
                v = src[(b * S_ + pos) * U_ + d];
            } else if (d < U_ - 2 + EMB_) {
                int wi = (int)src[(b * S_ + pos) * U_ + (U_ - 2)];
                v = wemb[wi * EMB_ + (d - (U_ - 2))];
            } else {
                int si = (int)src[(b * S_ + pos) * U_ + (U_ - 1)];
                v = semb[si * EMB_ + (d - (U_ - 2 + EMB_))];
            }
            int k = d >> 1;
            float div = expf((float)(2 * k) * negln);
            float ang = (float)b * div;
            v += (d & 1) ? cosf(ang) : sinf(ang);
            xs[pos][d] = v;
        }
    }
    __syncthreads();

    const float rs17 = 0.24253562503633297f;

    for (int l = 0; l < NL_; ++l) {
        for (int t = tid; t < 3 * D_ * D_; t += 512) wq_s[t] = qkv_w[l * 3 * D_ * D_ + t];
        for (int t = tid; t < D_ * D_; t += 512)     wo_s[t] = out_w[l * D_ * D_ + t];
        for (int t = tid; t < FF_ * D_; t += 512)    w1_s[t] = lin1_w[l * FF_ * D_ + t];
        for (int t = tid; t < D_ * FF_; t += 512)    w2_s[t] = lin2_w[l * D_ * FF_ + t];
        for (int t = tid; t < 3 * D_ + 6 * D_ + FF_; t += 512) {
            if      (t < 3 * D_)          bq_s[t]            = qkv_b[l * 3 * D_ + t];
            else if (t < 3 * D_ + D_)     bo_s[t - 3 * D_]   = out_b[l * D_ + (t - 3 * D_)];
            else if (t < 3 * D_ + 2 * D_) l1w_s[t - 4 * D_]  = ln1_w[l * D_ + (t - 4 * D_)];
            else if (t < 3 * D_ + 3 * D_) l1b_s[t - 5 * D_]  = ln1_b[l * D_ + (t - 5 * D_)];
            else if (t < 3 * D_ + 4 * D_) l2w_s[t - 6 * D_]  = ln2_w[l * D_ + (t - 6 * D_)];
            else if (t < 3 * D_ + 5 * D_) l2b_s[t - 7 * D_]  = ln2_b[l * D_ + (t - 7 * D_)];
            else if (t < 3 * D_ + 6 * D_) b2_s[t - 8 * D_]   = lin2_b[l * D_ + (t - 8 * D_)];
            else                          b1_s[t - 9 * D_]   = lin1_b[l * FF_ + (t - 9 * D_)];
        }
        __syncthreads();

        // ---- qkv projection, r-major: lane = pos, wave owns rows r = wv_+8k.
        // Weight reads wave-uniform (broadcast); xs reads stride-35 (free).
        for (int r = wv_; r < 3 * D_; r += 8) {
            const float* wrow = wq_s + r * D_;
            float aE = bq_s[r], aO = 0.f;
            #pragma unroll
            for (int d = 0; d < D_; d += 2) {
                aE += xs[lane][d] * wrow[d];
                aO += xs[lane][d + 1] * wrow[d + 1];
            }
            float acc = aE + aO;
            if (r < D_) {
                int h = (r >= 17), dd = r - h * 17;
                qsh[h][lane][dd] = acc;
            } else if (r < 2 * D_) {
                int rr = r - D_; int h = (rr >= 17), dd = rr - h * 17;
                ksh[h][lane][dd] = acc;
            } else {
                int rr = r - 2 * D_; int h = (rr >= 17), dd = rr - h * 17;
                vsh[h][lane][dd] = acc;
            }
        }
        __syncthreads();

        // ---- attention, 4-way key-parallel: tid = c*128 + h*64 + qi.
        // K/V reads: b128 broadcast (whole wave reads same key row).
        {
            int c = tid >> 7, hq = tid & 127;
            int h = hq >> 6, qi = hq & 63;
            float qv[17], acc[17];
            #pragma unroll
            for (int d = 0; d < 17; ++d) { qv[d] = qsh[h][qi][d]; acc[d] = 0.f; }
            float ssum = 0.f;
            int j0 = c * 16;
            for (int jj = 0; jj < 16; ++jj) {
                int j = j0 + jj;
                const float4* kr = (const float4*)ksh[h][j];
                const float4* vr = (const float4*)vsh[h][j];
                float4 k0 = kr[0], k1 = kr[1], k2 = kr[2], k3 = kr[3];
                float  k16 = ksh[h][j][16];
                float4 v0 = vr[0], v1 = vr[1], v2 = vr[2], v3 = vr[3];
                float  v16 = vsh[h][j][16];
                float sE = qv[0]*k0.x + qv[2]*k0.z + qv[4]*k1.x + qv[6]*k1.z +
                           qv[8]*k2.x + qv[10]*k2.z + qv[12]*k3.x + qv[14]*k3.z;
                float sO = qv[1]*k0.y + qv[3]*k0.w + qv[5]*k1.y + qv[7]*k1.w +
                           qv[9]*k2.y + qv[11]*k2.w + qv[13]*k3.y + qv[15]*k3.w;
                float sc = sE + sO + qv[16]*k16;
                float e = __expf(sc * rs17);
                ssum += e;
                acc[0] += e*v0.x;  acc[1] += e*v0.y;  acc[2] += e*v0.z;  acc[3] += e*v0.w;
                acc[4] += e*v1.x;  acc[5] += e*v1.y;  acc[6] += e*v1.z;  acc[7] += e*v1.w;
                acc[8] += e*v2.x;  acc[9] += e*v2.y;  acc[10] += e*v2.z; acc[11] += e*v2.w;
                acc[12] += e*v3.x; acc[13] += e*v3.y; acc[14] += e*v3.z; acc[15] += e*v3.w;
                acc[16] += e*v16;
            }
            #pragma unroll
            for (int d = 0; d < 17; ++d) pacc[c][hq][d] = acc[d];
            pacc[c][hq][17] = ssum;
        }
        __syncthreads();

        // ---- combine partial softmax (128 threads)
        if (tid < 128) {
            int h = tid >> 6, qi = tid & 63;
            int off = h * 17;
            float ssum = pacc[0][tid][17] + pacc[1][tid][17] +
                         pacc[2][tid][17] + pacc[3][tid][17];
            float inv = 1.f / ssum;
            #pragma unroll
            for (int d = 0; d < 17; ++d)
                att[qi][off + d] = (pacc[0][tid][d] + pacc[1][tid][d] +
                                    pacc[2][tid][d] + pacc[3][tid][d]) * inv;
        }
        __syncthreads();

        // ---- out proj + residual, r-major (weights broadcast, att stride-35)
        for (int d = wv_; d < D_; d += 8) {
            const float* wrow = wo_s + d * D_;
            float aE = bo_s[d], aO = 0.f;
            #pragma unroll
            for (int e = 0; e < D_; e += 2) {
                aE += att[lane][e] * wrow[e];
                aO += att[lane][e + 1] * wrow[e + 1];
            }
            tmp[lane][d] = xs[lane][d] + aE + aO;
        }
        __syncthreads();

        // ---- LN1
        if (tid < S_) {
            int row = tid;
            float sA = 0.f, sB = 0.f;
            #pragma unroll
            for (int d = 0; d < D_; d += 2) { sA += tmp[row][d]; sB += tmp[row][d + 1]; }
            float mu = (sA + sB) * (1.0f / D_);
            float vA = 0.f, vB = 0.f;
            #pragma unroll
            for (int d = 0; d < D_; d += 2) {
                float t0 = tmp[row][d] - mu;     vA += t0 * t0;
                float t1 = tmp[row][d + 1] - mu; vB += t1 * t1;
            }
            float rstd = rsqrtf((vA + vB) * (1.0f / D_) + 1e-5f);
            #pragma unroll
            for (int d = 0; d < D_; ++d)
                xs[row][d] = (tmp[row][d] - mu) * rstd * l1w_s[d] + l1b_s[d];
        }
        __syncthreads();

        // ---- FF1 (34 -> 4, relu)
        if (tid < 256) {
            int pos = tid >> 2, f = tid & 3;
            const float* wrow = w1_s + f * D_;
            float aE = b1_s[f], aO = 0.f;
            #pragma unroll
            for (int d = 0; d < D_; d += 2) {
                aE += xs[pos][d] * wrow[d];
                aO += xs[pos][d + 1] * wrow[d + 1];
            }
            ffh[pos][f] = fmaxf(aE + aO, 0.f);
        }
        __syncthreads();

        // ---- FF2 (4 -> 34) + residual, r-major
        for (int d = wv_; d < D_; d += 8) {
            const float* wrow = w2_s + d * FF_;
            float acc = b2_s[d] + ffh[lane][0] * wrow[0] + ffh[lane][1] * wrow[1] +
                        ffh[lane][2] * wrow[2] + ffh[lane][3] * wrow[3];
            tmp[lane][d] = xs[lane][d] + acc;
        }
        __syncthreads();

        // ---- LN2
        if (tid < S_) {
            int row = tid;
            float sA = 0.f, sB = 0.f;
            #pragma unroll
            for (int d = 0; d < D_; d += 2) { sA += tmp[row][d]; sB += tmp[row][d + 1]; }
            float mu = (sA + sB) * (1.0f / D_);
            float vA = 0.f, vB = 0.f;
            #pragma unroll
            for (int d = 0; d < D_; d += 2) {
                float t0 = tmp[row][d] - mu;     vA += t0 * t0;
                float t1 = tmp[row][d + 1] - mu; vB += t1 * t1;
            }
            float rstd = rsqrtf((vA + vB) * (1.0f / D_) + 1e-5f);
            #pragma unroll
            for (int d = 0; d < D_; ++d)
                xs[row][d] = (tmp[row][d] - mu) * rstd * l2w_s[d] + l2b_s[d];
        }
        __syncthreads();
    }

    // ---- final LayerNorm
    if (tid < S_) {
        int row = tid;
        float sA = 0.f, sB = 0.f;
        #pragma unroll
        for (int d = 0; d < D_; d += 2) { sA += xs[row][d]; sB += xs[row][d + 1]; }
        float mu = (sA + sB) * (1.0f / D_);
        float vA = 0.f, vB = 0.f;
        #pragma unroll
        for (int d = 0; d < D_; d += 2) {
            float t0 = xs[row][d] - mu;     vA += t0 * t0;
            float t1 = xs[row][d + 1] - mu; vB += t1 * t1;
        }
        float rstd = rsqrtf((vA + vB) * (1.0f / D_) + 1e-5f);
        #pragma unroll
        for (int d = 0; d < D_; ++d)
            xs[row][d] = (xs[row][d] - mu) * rstd * norm_w[d] + norm_b[d];
    }
    __syncthreads();

    // ---- memory = x @ eo_w.T + eo_b
    if (tid < S_ * DD_) {
        int pos = tid / DD_, r = tid % DD_;
        const float* wrow = eo_w + r * D_;
        float aE = eo_b[r], aO = 0.f;
        #pragma unroll
        for (int d = 0; d < D_; d += 2) {
            aE += xs[pos][d] * wrow[d];
            aO += xs[pos][d + 1] * wrow[d + 1];
        }
        mem[(b * S_ + pos) * DD_ + r] = aE + aO;
    }

    if (tid < S_) {
        out[(b * S_ + tid) * 5 + 3] = src[(b * S_ + tid) * U_ + (U_ - 2)];
        out[(b * S_ + tid) * 5 + 4] = src[(b * S_ + tid) * U_ + (U_ - 1)];
    }
}

// ---------------------------------------------------------------------------
// Kernel B: incremental autoregressive decoder (R6 algebra, R7 register diet).
// Pinned (VGPR): SA-path weights (Wqp/Bqp/Wk/Bk/WVp/bvp/Bso/N1) + per-lane
// ck/cvp/sk/sv  => ~230 regs, under the 256 arch-VGPR cliff (R6's 436-value
// pin spilled to AGPR/scratch and regressed). Everything consumed after the
// SA reduction (Wcq/Bcq/Bco/N2 + FF tail = 60 floats/layer) lives in LDS,
// loaded as 15x float4 at layer top with NO pin: first use is ~500cy
// downstream, the compiler's natural lgkmcnt wait is slack-hidden.
// ---------------------------------------------------------------------------
#define PIN(x) asm volatile("" : "+v"(x))

template <int CTRL>
__device__ __forceinline__ float dpp_add(float v) {
    int t = __builtin_amdgcn_update_dpp(0, __float_as_int(v), CTRL, 0xf, 0xf, true);
    return v + __int_as_float(t);
}

__device__ __forceinline__ float wave_sum_l63(float v) {
    v = dpp_add<0x111>(v);
    v = dpp_add<0x112>(v);
    v = dpp_add<0x114>(v);
    v = dpp_add<0x118>(v);
    v = dpp_add<0x142>(v);
    v = dpp_add<0x143>(v);
    return v;
}

__device__ __forceinline__ float bcast63(float v) {
    return __int_as_float(__builtin_amdgcn_readlane(__float_as_int(v), 63));
}

__device__ __forceinline__ void ln3e(float z0, float z1, float z2,
                                     float w0, float w1, float w2,
                                     float b0, float b1, float b2,
                                     float& o0, float& o1, float& o2) {
    float s1 = (z0 + z1) + z2;
    float s2 = fmaf(z0, z0, fmaf(z1, z1, z2 * z2));
    float mu = s1 * (1.0f / 3.0f);
    float vpe = fmaf(s2, (1.0f / 3.0f), fmaf(-mu, mu, 1e-5f));
    float rstd = __builtin_amdgcn_rsqf(vpe);
    o0 = fmaf(z0 - mu, rstd * w0, b0);
    o1 = fmaf(z1 - mu, rstd * w1, b1);
    o2 = fmaf(z2 - mu, rstd * w2, b2);
}

__global__ __launch_bounds__(64, 1) void dec_kernel(
    const float* __restrict__ mem,
    const float* __restrict__ sa_qkv_w, const float* __restrict__ sa_qkv_b,
    const float* __restrict__ sa_out_w, const float* __restrict__ sa_out_b,
    const float* __restrict__ gln1_w, const float* __restrict__ gln1_b,
    const float* __restrict__ ca_qkv_w, const float* __restrict__ ca_qkv_b,
    const float* __restrict__ ca_out_w, const float* __restrict__ ca_out_b,
    const float* __restrict__ gln2_w, const float* __restrict__ gln2_b,
    const float* __restrict__ l1_w, const float* __restrict__ l1_b,
    const float* __restrict__ l2_w, const float* __restrict__ l2_b,
    const float* __restrict__ gln3_w, const float* __restrict__ gln3_b,
    float* __restrict__ out)
{
    const int b = blockIdx.x;
    const int lane = threadIdx.x;
    const float LOG2E = 1.4426950408889634f;
    const float rs3 = 0.5773502691896258f;
    const float QS = rs3 * LOG2E;

    // ---- LDS-resident per-layer tail weights (60-slot rows, 16B aligned):
    // 0-8 Wcq | 9-11 Bcq | 12-14 Bco | 15-17 N2w | 18-20 N2b |
    // 21-32 F1w | 33-36 F1b | 37-48 F2w | 49-51 F2b | 52-54 N3w | 55-57 N3b
    __shared__ __align__(16) float fst[NL_][60];
    for (int t = lane; t < NL_ * 60; t += 64) {
        int l = t / 60, s = t % 60;
        float v = 0.f;
        if      (s < 9)  v = ca_qkv_w[l * 27 + s];            // Wcq rows 0..2
        else if (s < 12) v = ca_qkv_b[l * 9 + (s - 9)];       // Bcq
        else if (s < 15) v = ca_out_b[l * 3 + (s - 12)];      // Bco
        else if (s < 18) v = gln2_w[l * 3 + (s - 15)];
        else if (s < 21) v = gln2_b[l * 3 + (s - 18)];
        else if (s < 33) v = l1_w[l * 12 + (s - 21)];
        else if (s < 37) v = l1_b[l * 4 + (s - 33)];
        else if (s < 49) v = l2_w[l * 12 + (s - 37)];
        else if (s < 52) v = l2_b[l * 3 + (s - 49)];
        else if (s < 55) v = gln3_w[l * 3 + (s - 52)];
        else if (s < 58) v = gln3_b[l * 3 + (s - 55)];
        fst[l][s] = v;
    }
    __syncthreads();

    // ---- pinned SA-path weights
    float Wqp[NL_][3][3], Bqp[NL_][3];      // q-proj pre-scaled by QS
    float Wk [NL_][3][3], Bk [NL_][3];
    float WVp[NL_][3][3], bvp[NL_][3];      // Wso*Wv, Wso*bv
    float Bso[NL_][3];
    float N1w[NL_][3], N1b[NL_][3];

    #pragma unroll
    for (int l = 0; l < NL_; ++l) {
        #pragma unroll
        for (int r = 0; r < 3; ++r) {
            Bqp[l][r] = sa_qkv_b[l * 9 + r] * QS;
            Bk [l][r] = sa_qkv_b[l * 9 + 3 + r];
            #pragma unroll
            for (int c = 0; c < 3; ++c) {
                Wqp[l][r][c] = sa_qkv_w[l * 27 + r * 3 + c] * QS;
                Wk [l][r][c] = sa_qkv_w[l * 27 + (3 + r) * 3 + c];
            }
            float a0 = 0.f, a1 = 0.f, a2 = 0.f, ab = 0.f;
            #pragma unroll
            for (int t = 0; t < 3; ++t) {
                float wso = sa_out_w[l * 9 + r * 3 + t];
                a0 += wso * sa_qkv_w[l * 27 + (6 + t) * 3 + 0];
                a1 += wso * sa_qkv_w[l * 27 + (6 + t) * 3 + 1];
                a2 += wso * sa_qkv_w[l * 27 + (6 + t) * 3 + 2];
                ab += wso * sa_qkv_b[l * 9 + 6 + t];
            }
            WVp[l][r][0] = a0; WVp[l][r][1] = a1; WVp[l][r][2] = a2;
            bvp[l][r] = ab;
            Bso[l][r] = sa_out_b[l * 3 + r];
            N1w[l][r] = gln1_w[l * 3 + r];  N1b[l][r] = gln1_b[l * 3 + r];
        }
    }

    // ---- per-lane cross-attn caches: ck scaled by QS, cv' = Wco*cv
    float m0 = mem[(b * S_ + lane) * DD_ + 0];
    float m1 = mem[(b * S_ + lane) * DD_ + 1];
    float m2 = mem[(b * S_ + lane) * DD_ + 2];

    float ck[NL_][3], cvp[NL_][3];
    #pragma unroll
    for (int l = 0; l < NL_; ++l) {
        float cvt[3];
        #pragma unroll
        for (int t = 0; t < 3; ++t) {
            cvt[t] = ca_qkv_w[l * 27 + (6 + t) * 3 + 0] * m0 +
                     ca_qkv_w[l * 27 + (6 + t) * 3 + 1] * m1 +
                     ca_qkv_w[l * 27 + (6 + t) * 3 + 2] * m2 + ca_qkv_b[l * 9 + 6 + t];
        }
        #pragma unroll
        for (int r = 0; r < 3; ++r) {
            float kk = ca_qkv_w[l * 27 + (3 + r) * 3 + 0] * m0 +
                       ca_qkv_w[l * 27 + (3 + r) * 3 + 1] * m1 +
                       ca_qkv_w[l * 27 + (3 + r) * 3 + 2] * m2 + ca_qkv_b[l * 9 + 3 + r];
            ck[l][r] = kk * QS;
            cvp[l][r] = ca_out_w[l * 9 + r * 3 + 0] * cvt[0] +
                        ca_out_w[l * 9 + r * 3 + 1] * cvt[1] +
                        ca_out_w[l * 9 + r * 3 + 2] * cvt[2];
        }
    }

    // ---- pin (SA set + per-lane caches; ~230 regs total live)
    #pragma unroll
    for (int l = 0; l < NL_; ++l) {
        #pragma unroll
        for (int r = 0; r < 3; ++r) {
            PIN(Bqp[l][r]); PIN(Bk[l][r]); PIN(bvp[l][r]); PIN(Bso[l][r]);
            PIN(N1w[l][r]); PIN(N1b[l][r]);
            PIN(ck[l][r]); PIN(cvp[l][r]);
            #pragma unroll
            for (int c = 0; c < 3; ++c) {
                PIN(Wqp[l][r][c]); PIN(Wk[l][r][c]); PIN(WVp[l][r][c]);
            }
        }
    }

    float sk[NL_][3] = {{0.f}}, sv[NL_][3] = {{0.f}};

    if (lane < 3) out[(b * S_ + 0) * 5 + lane] = 0.f;

    float y0 = 0.f, y1 = 0.f, y2 = 0.f;

    for (int i = 0; i < S_ - 1; ++i) {
        float msa = (lane <= i) ? 0.f : -1.0e30f;
        #pragma unroll
        for (int l = 0; l < NL_; ++l) {
            // ---- tail weights: 15x float4 from LDS, no pin (slack-hidden)
            float wv[60];
            {
                const float4* fp = (const float4*)fst[l];
                #pragma unroll
                for (int k = 0; k < 15; ++k) {
                    float4 t4 = fp[k];
                    wv[4 * k + 0] = t4.x; wv[4 * k + 1] = t4.y;
                    wv[4 * k + 2] = t4.z; wv[4 * k + 3] = t4.w;
                }
            }

            // ---- causal self-attention (q pre-scaled; v' = Wso*v)
            float q0 = fmaf(Wqp[l][0][0], y0, fmaf(Wqp[l][0][1], y1, fmaf(Wqp[l][0][2], y2, Bqp[l][0])));
            float q1 = fmaf(Wqp[l][1][0], y0, fmaf(Wqp[l][1][1], y1, fmaf(Wqp[l][1][2], y2, Bqp[l][1])));
            float q2 = fmaf(Wqp[l][2][0], y0, fmaf(Wqp[l][2][1], y1, fmaf(Wqp[l][2][2], y2, Bqp[l][2])));
            float k0 = fmaf(Wk[l][0][0], y0, fmaf(Wk[l][0][1], y1, fmaf(Wk[l][0][2], y2, Bk[l][0])));
            float k1 = fmaf(Wk[l][1][0], y0, fmaf(Wk[l][1][1], y1, fmaf(Wk[l][1][2], y2, Bk[l][1])));
            float k2 = fmaf(Wk[l][2][0], y0, fmaf(Wk[l][2][1], y1, fmaf(Wk[l][2][2], y2, Bk[l][2])));
            float v0 = fmaf(WVp[l][0][0], y0, fmaf(WVp[l][0][1], y1, fmaf(WVp[l][0][2], y2, bvp[l][0])));
            float v1 = fmaf(WVp[l][1][0], y0, fmaf(WVp[l][1][1], y1, fmaf(WVp[l][1][2], y2, bvp[l][1])));
            float v2 = fmaf(WVp[l][2][0], y0, fmaf(WVp[l][2][1], y1, fmaf(WVp[l][2][2], y2, bvp[l][2])));
            if (lane == i) {
                sk[l][0] = k0; sk[l][1] = k1; sk[l][2] = k2;
                sv[l][0] = v0; sv[l][1] = v1; sv[l][2] = v2;
            }
            float sc = fmaf(q0, sk[l][0], fmaf(q1, sk[l][1], fmaf(q2, sk[l][2], msa)));
            float e = __builtin_amdgcn_exp2f(sc);
            float es  = bcast63(wave_sum_l63(e));
            float ev0 = bcast63(wave_sum_l63(e * sv[l][0]));
            float ev1 = bcast63(wave_sum_l63(e * sv[l][1]));
            float ev2 = bcast63(wave_sum_l63(e * sv[l][2]));
            float t0 = y0 + Bso[l][0], t1 = y1 + Bso[l][1], t2 = y2 + Bso[l][2];
            float z0 = fmaf(t0, es, ev0);
            float z1 = fmaf(t1, es, ev1);
            float z2 = fmaf(t2, es, ev2);
            ln3e(z0, z1, z2, N1w[l][0], N1w[l][1], N1w[l][2],
                 N1b[l][0], N1b[l][1], N1b[l][2], y0, y1, y2);

            // ---- cross-attention (Wcq/Bcq from wv[]; scale folded into ck)
            float p0 = fmaf(wv[0], y0, fmaf(wv[1], y1, fmaf(wv[2], y2, wv[9])));
            float p1 = fmaf(wv[3], y0, fmaf(wv[4], y1, fmaf(wv[5], y2, wv[10])));
            float p2 = fmaf(wv[6], y0, fmaf(wv[7], y1, fmaf(wv[8], y2, wv[11])));
            float sc2 = fmaf(p0, ck[l][0], fmaf(p1, ck[l][1], p2 * ck[l][2]));
            float e2 = __builtin_amdgcn_exp2f(sc2);
            float cs  = bcast63(wave_sum_l63(e2));
            float cw0 = bcast63(wave_sum_l63(e2 * cvp[l][0]));
            float cw1 = bcast63(wave_sum_l63(e2 * cvp[l][1]));
            float cw2 = bcast63(wave_sum_l63(e2 * cvp[l][2]));
            float u0 = y0 + wv[12], u1 = y1 + wv[13], u2 = y2 + wv[14];
            z0 = fmaf(u0, cs, cw0);
            z1 = fmaf(u1, cs, cw1);
            z2 = fmaf(u2, cs, cw2);
            ln3e(z0, z1, z2, wv[15], wv[16], wv[17],
                 wv[18], wv[19], wv[20], y0, y1, y2);

            // ---- feed-forward 3 -> 4 -> 3 (relu)
            float h0 = fmaxf(fmaf(wv[21], y0, fmaf(wv[22], y1, fmaf(wv[23], y2, wv[33]))), 0.f);
            float h1 = fmaxf(fmaf(wv[24], y0, fmaf(wv[25], y1, fmaf(wv[26], y2, wv[34]))), 0.f);
            float h2 = fmaxf(fmaf(wv[27], y0, fmaf(wv[28], y1, fmaf(wv[29], y2, wv[35]))), 0.f);
            float h3 = fmaxf(fmaf(wv[30], y0, fmaf(wv[31], y1, fmaf(wv[32], y2, wv[36]))), 0.f);
            float f0 = fmaf(wv[37], h0, fmaf(wv[38], h1, fmaf(wv[39], h2, fmaf(wv[40], h3, wv[49]))));
            float f1 = fmaf(wv[41], h0, fmaf(wv[42], h1, fmaf(wv[43], h2, fmaf(wv[44], h3, wv[50]))));
            float f2 = fmaf(wv[45], h0, fmaf(wv[46], h1, fmaf(wv[47], h2, fmaf(wv[48], h3, wv[51]))));
            ln3e(y0 + f0, y1 + f1, y2 + f2, wv[52], wv[53], wv[54],
                 wv[55], wv[56], wv[57], y0, y1, y2);
        }
        if (lane == 0) {
            out[(b * S_ + i + 1) * 5 + 0] = y0;
            out[(b * S_ + i + 1) * 5 + 1] = y1;
            out[(b * S_ + i + 1) * 5 + 2] = y2;
        }
    }
}

// ---------------------------------------------------------------------------
extern "C" void kernel_launch(void* const* d_in, const int* in_sizes, int n_in,
                              void* d_out, int out_size, void* d_ws, size_t ws_size,
                              hipStream_t stream) {
    const float* src  = (const float*)d_in[0];
    const float* wemb = (const float*)d_in[1];
    const float* semb = (const float*)d_in[2];

    float* mem = (float*)d_ws;           // [B,S,3] scratch
    float* out = (float*)d_out;          // [B,S,5]

    enc_kernel<<<B_, 512, 0, stream>>>(
        src, wemb, semb,
        (const float*)d_in[3],  (const float*)d_in[4],
        (const float*)d_in[5],  (const float*)d_in[6],
        (const float*)d_in[7],  (const float*)d_in[8],
        (const float*)d_in[9],  (const float*)d_in[10],
        (const float*)d_in[11], (const float*)d_in[12],
        (const float*)d_in[13], (const float*)d_in[14],
        (const float*)d_in[15], (const float*)d_in[16],
        (const float*)d_in[17], (const float*)d_in[18],
        mem, out);

    dec_kernel<<<B_, 64, 0, stream>>>(
        mem,
        (const float*)d_in[19], (const float*)d_in[20],
        (const float*)d_in[21], (const float*)d_in[22],
        (const float*)d_in[23], (const float*)d_in[24],
        (const float*)d_in[25], (const float*)d_in[26],
        (const float*)d_in[27], (const float*)d_in[28],
        (const float*)d_in[29], (const float*)d_in[30],
        (const float*)d_in[31], (const float*)d_in[32],
        (const float*)d_in[33], (const float*)d_in[34],
        (const float*)d_in[35], (const float*)d_in[36],
        out);
}

// Round 8
// 366.527 us; speedup vs baseline: 1.0871x; 1.0017x over previous
//
#include <hip/hip_runtime.h>
#include <math.h>

#define B_ 64
#define S_ 64
#define U_ 16
#define EMB_ 10
#define D_ 34
#define DD_ 3
#define FF_ 4
#define NL_ 4

// ---------------------------------------------------------------------------
// Kernel A: encoder. One block per batch element, 512 threads (8 waves).
// R8: NO LDS weight staging. Weights are read directly from global with
// readfirstlane-uniformized row indices -> s_load -> SGPR fma operands
// (constant-cached, shared across all 64 blocks). Activation rows are loaded
// into registers once per stage and reused across all rows a wave computes.
// ---------------------------------------------------------------------------
__global__ __launch_bounds__(512) void enc_kernel(
    const float* __restrict__ src, const float* __restrict__ wemb,
    const float* __restrict__ semb,
    const float* __restrict__ qkv_w, const float* __restrict__ qkv_b,
    const float* __restrict__ out_w, const float* __restrict__ out_b,
    const float* __restrict__ ln1_w, const float* __restrict__ ln1_b,
    const float* __restrict__ lin1_w, const float* __restrict__ lin1_b,
    const float* __restrict__ lin2_w, const float* __restrict__ lin2_b,
    const float* __restrict__ ln2_w, const float* __restrict__ ln2_b,
    const float* __restrict__ norm_w, const float* __restrict__ norm_b,
    const float* __restrict__ eo_w, const float* __restrict__ eo_b,
    float* __restrict__ mem, float* __restrict__ out)
{
    const int b = blockIdx.x;
    const int tid = threadIdx.x;
    const int wv_ = tid >> 6;        // wave id 0..7
    const int lane = tid & 63;

    __shared__ float xs[S_][D_ + 1];                 // stride 35, conflict-free
    __shared__ float tmp[S_][D_ + 1];
    __shared__ float att[S_][D_ + 1];
    __shared__ __align__(16) float qsh[2][S_][21];
    __shared__ __align__(16) float ksh[2][S_][20];   // b128-aligned rows
    __shared__ __align__(16) float vsh[2][S_][20];
    __shared__ float ffh[S_][5];
    __shared__ float pacc[4][128][19];

    // ---- embed + positional encoding (pe row b added to ALL positions)
    const float negln = -logf(10000.0f) / (float)D_;
    #pragma unroll
    for (int rep = 0; rep < 5; ++rep) {
        int idx = tid + rep * 512;
        if (idx < S_ * D_) {
            int pos = idx / D_, d = idx % D_;
            float v;
            if (d < U_ - 2) {
                v = src[(b * S_ + pos) * U_ + d];
            } else if (d < U_ - 2 + EMB_) {
                int wi = (int)src[(b * S_ + pos) * U_ + (U_ - 2)];
                v = wemb[wi * EMB_ + (d - (U_ - 2))];
            } else {
                int si = (int)src[(b * S_ + pos) * U_ + (U_ - 1)];
                v = semb[si * EMB_ + (d - (U_ - 2 + EMB_))];
            }
            int k = d >> 1;
            float div = __expf((float)(2 * k) * negln);
            float ang = (float)b * div;
            v += (d & 1) ? __cosf(ang) : __sinf(ang);
            xs[pos][d] = v;
        }
    }
    __syncthreads();

    const float rs17 = 0.24253562503633297f;

    for (int l = 0; l < NL_; ++l) {
        const float* Wq = qkv_w + l * 3 * D_ * D_;
        const float* Bq = qkv_b + l * 3 * D_;

        // ---- qkv: lane = pos; wave owns rows r = wv_ + 8k (k < 13).
        // Row index uniformized -> weights via s_load; x row in registers.
        {
            float xr[D_];
            #pragma unroll
            for (int d = 0; d < D_; ++d) xr[d] = xs[lane][d];
            for (int rb = 0; rb < 13; ++rb) {
                int r = wv_ + (rb << 3);
                if (r < 3 * D_) {
                    int ru = __builtin_amdgcn_readfirstlane(r);
                    const float* wrow = Wq + ru * D_;
                    float aE = Bq[ru], aO = 0.f;
                    #pragma unroll
                    for (int d = 0; d < D_; d += 2) {
                        aE = fmaf(xr[d], wrow[d], aE);
                        aO = fmaf(xr[d + 1], wrow[d + 1], aO);
                    }
                    float acc = aE + aO;
                    if (ru < D_)          { int h = (ru >= 17), dd = ru - h * 17; qsh[h][lane][dd] = acc; }
                    else if (ru < 2 * D_) { int rr = ru - D_;     int h = (rr >= 17), dd = rr - h * 17; ksh[h][lane][dd] = acc; }
                    else                  { int rr = ru - 2 * D_; int h = (rr >= 17), dd = rr - h * 17; vsh[h][lane][dd] = acc; }
                }
            }
        }
        __syncthreads();

        // ---- attention, 4-way key-parallel: tid = c*128 + h*64 + qi
        {
            int c = tid >> 7, hq = tid & 127;
            int h = hq >> 6, qi = hq & 63;
            float qv[17], acc[17];
            #pragma unroll
            for (int d = 0; d < 17; ++d) { qv[d] = qsh[h][qi][d]; acc[d] = 0.f; }
            float ssum = 0.f;
            int j0 = c * 16;
            for (int jj = 0; jj < 16; ++jj) {
                int j = j0 + jj;
                const float4* kr = (const float4*)ksh[h][j];
                const float4* vr = (const float4*)vsh[h][j];
                float4 k0 = kr[0], k1 = kr[1], k2 = kr[2], k3 = kr[3];
                float  k16 = ksh[h][j][16];
                float4 v0 = vr[0], v1 = vr[1], v2 = vr[2], v3 = vr[3];
                float  v16 = vsh[h][j][16];
                float sE = qv[0]*k0.x + qv[2]*k0.z + qv[4]*k1.x + qv[6]*k1.z +
                           qv[8]*k2.x + qv[10]*k2.z + qv[12]*k3.x + qv[14]*k3.z;
                float sO = qv[1]*k0.y + qv[3]*k0.w + qv[5]*k1.y + qv[7]*k1.w +
                           qv[9]*k2.y + qv[11]*k2.w + qv[13]*k3.y + qv[15]*k3.w;
                float sc = sE + sO + qv[16]*k16;
                float e = __expf(sc * rs17);
                ssum += e;
                acc[0] += e*v0.x;  acc[1] += e*v0.y;  acc[2] += e*v0.z;  acc[3] += e*v0.w;
                acc[4] += e*v1.x;  acc[5] += e*v1.y;  acc[6] += e*v1.z;  acc[7] += e*v1.w;
                acc[8] += e*v2.x;  acc[9] += e*v2.y;  acc[10] += e*v2.z; acc[11] += e*v2.w;
                acc[12] += e*v3.x; acc[13] += e*v3.y; acc[14] += e*v3.z; acc[15] += e*v3.w;
                acc[16] += e*v16;
            }
            #pragma unroll
            for (int d = 0; d < 17; ++d) pacc[c][hq][d] = acc[d];
            pacc[c][hq][17] = ssum;
        }
        __syncthreads();

        if (tid < 128) {
            int h = tid >> 6, qi = tid & 63;
            int off = h * 17;
            float ssum = pacc[0][tid][17] + pacc[1][tid][17] +
                         pacc[2][tid][17] + pacc[3][tid][17];
            float inv = 1.f / ssum;
            #pragma unroll
            for (int d = 0; d < 17; ++d)
                att[qi][off + d] = (pacc[0][tid][d] + pacc[1][tid][d] +
                                    pacc[2][tid][d] + pacc[3][tid][d]) * inv;
        }
        __syncthreads();

        // ---- out proj + residual: lane = pos, rows d = wv_ + 8k (k < 5)
        {
            float ar[D_];
            #pragma unroll
            for (int e = 0; e < D_; ++e) ar[e] = att[lane][e];
            const float* Wo = out_w + l * D_ * D_;
            const float* Bo = out_b + l * D_;
            for (int rb = 0; rb < 5; ++rb) {
                int d = wv_ + (rb << 3);
                if (d < D_) {
                    int du = __builtin_amdgcn_readfirstlane(d);
                    const float* wrow = Wo + du * D_;
                    float aE = Bo[du], aO = 0.f;
                    #pragma unroll
                    for (int e = 0; e < D_; e += 2) {
                        aE = fmaf(ar[e], wrow[e], aE);
                        aO = fmaf(ar[e + 1], wrow[e + 1], aO);
                    }
                    tmp[lane][du] = xs[lane][du] + aE + aO;
                }
            }
        }
        __syncthreads();

        // ---- LN1 (weights via uniform global reads -> s_load)
        if (tid < S_) {
            int row = tid;
            float sA = 0.f, sB = 0.f;
            #pragma unroll
            for (int d = 0; d < D_; d += 2) { sA += tmp[row][d]; sB += tmp[row][d + 1]; }
            float mu = (sA + sB) * (1.0f / D_);
            float vA = 0.f, vB = 0.f;
            #pragma unroll
            for (int d = 0; d < D_; d += 2) {
                float t0 = tmp[row][d] - mu;     vA += t0 * t0;
                float t1 = tmp[row][d + 1] - mu; vB += t1 * t1;
            }
            float rstd = rsqrtf((vA + vB) * (1.0f / D_) + 1e-5f);
            #pragma unroll
            for (int d = 0; d < D_; ++d)
                xs[row][d] = (tmp[row][d] - mu) * rstd * ln1_w[l * D_ + d] + ln1_b[l * D_ + d];
        }
        __syncthreads();

        // ---- FF1 (34 -> 4, relu): waves 0..3, f = wv_, lane = pos
        if (wv_ < 4) {
            int fu = __builtin_amdgcn_readfirstlane(wv_);
            const float* wrow = lin1_w + l * FF_ * D_ + fu * D_;
            float aE = lin1_b[l * FF_ + fu], aO = 0.f;
            #pragma unroll
            for (int d = 0; d < D_; d += 2) {
                aE = fmaf(xs[lane][d], wrow[d], aE);
                aO = fmaf(xs[lane][d + 1], wrow[d + 1], aO);
            }
            ffh[lane][fu] = fmaxf(aE + aO, 0.f);
        }
        __syncthreads();

        // ---- FF2 (4 -> 34) + residual: lane = pos, rows d = wv_ + 8k
        {
            float h0 = ffh[lane][0], h1 = ffh[lane][1],
                  h2 = ffh[lane][2], h3 = ffh[lane][3];
            const float* W2 = lin2_w + l * D_ * FF_;
            const float* B2 = lin2_b + l * D_;
            for (int rb = 0; rb < 5; ++rb) {
                int d = wv_ + (rb << 3);
                if (d < D_) {
                    int du = __builtin_amdgcn_readfirstlane(d);
                    const float* wrow = W2 + du * FF_;
                    float acc = fmaf(h0, wrow[0], fmaf(h1, wrow[1],
                                fmaf(h2, wrow[2], fmaf(h3, wrow[3], B2[du]))));
                    tmp[lane][du] = xs[lane][du] + acc;
                }
            }
        }
        __syncthreads();

        // ---- LN2
        if (tid < S_) {
            int row = tid;
            float sA = 0.f, sB = 0.f;
            #pragma unroll
            for (int d = 0; d < D_; d += 2) { sA += tmp[row][d]; sB += tmp[row][d + 1]; }
            float mu = (sA + sB) * (1.0f / D_);
            float vA = 0.f, vB = 0.f;
            #pragma unroll
            for (int d = 0; d < D_; d += 2) {
                float t0 = tmp[row][d] - mu;     vA += t0 * t0;
                float t1 = tmp[row][d + 1] - mu; vB += t1 * t1;
            }
            float rstd = rsqrtf((vA + vB) * (1.0f / D_) + 1e-5f);
            #pragma unroll
            for (int d = 0; d < D_; ++d)
                xs[row][d] = (tmp[row][d] - mu) * rstd * ln2_w[l * D_ + d] + ln2_b[l * D_ + d];
        }
        __syncthreads();
    }

    // ---- final LayerNorm
    if (tid < S_) {
        int row = tid;
        float sA = 0.f, sB = 0.f;
        #pragma unroll
        for (int d = 0; d < D_; d += 2) { sA += xs[row][d]; sB += xs[row][d + 1]; }
        float mu = (sA + sB) * (1.0f / D_);
        float vA = 0.f, vB = 0.f;
        #pragma unroll
        for (int d = 0; d < D_; d += 2) {
            float t0 = xs[row][d] - mu;     vA += t0 * t0;
            float t1 = xs[row][d + 1] - mu; vB += t1 * t1;
        }
        float rstd = rsqrtf((vA + vB) * (1.0f / D_) + 1e-5f);
        #pragma unroll
        for (int d = 0; d < D_; ++d)
            xs[row][d] = (xs[row][d] - mu) * rstd * norm_w[d] + norm_b[d];
    }
    __syncthreads();

    // ---- memory = x @ eo_w.T + eo_b : waves 0..2, r = wv_, lane = pos
    if (wv_ < 3) {
        int ru = __builtin_amdgcn_readfirstlane(wv_);
        const float* wrow = eo_w + ru * D_;
        float aE = eo_b[ru], aO = 0.f;
        #pragma unroll
        for (int d = 0; d < D_; d += 2) {
            aE = fmaf(xs[lane][d], wrow[d], aE);
            aO = fmaf(xs[lane][d + 1], wrow[d + 1], aO);
        }
        mem[(b * S_ + lane) * DD_ + ru] = aE + aO;
    }

    if (tid < S_) {
        out[(b * S_ + tid) * 5 + 3] = src[(b * S_ + tid) * U_ + (U_ - 2)];
        out[(b * S_ + tid) * 5 + 4] = src[(b * S_ + tid) * U_ + (U_ - 1)];
    }
}

// ---------------------------------------------------------------------------
// Kernel B: incremental autoregressive decoder (R6 algebra, lower pressure).
// Pinned (192): Wqp/Bqp/Wk/Bk/WVp/bvp + ck/cvp. Bso/N1 moved to LDS.
// Tail loaded in 2 float4 groups: g1 (Bso/N1/CA/N2, 8xf4) at layer top,
// g2 (FF tail, 10xf4) issued under the SA DPP-reduction chain.
// ---------------------------------------------------------------------------
#define PIN(x) asm volatile("" : "+v"(x))

template <int CTRL>
__device__ __forceinline__ float dpp_add(float v) {
    int t = __builtin_amdgcn_update_dpp(0, __float_as_int(v), CTRL, 0xf, 0xf, true);
    return v + __int_as_float(t);
}

__device__ __forceinline__ float wave_sum_l63(float v) {
    v = dpp_add<0x111>(v);
    v = dpp_add<0x112>(v);
    v = dpp_add<0x114>(v);
    v = dpp_add<0x118>(v);
    v = dpp_add<0x142>(v);
    v = dpp_add<0x143>(v);
    return v;
}

__device__ __forceinline__ float bcast63(float v) {
    return __int_as_float(__builtin_amdgcn_readlane(__float_as_int(v), 63));
}

__device__ __forceinline__ void ln3e(float z0, float z1, float z2,
                                     float w0, float w1, float w2,
                                     float b0, float b1, float b2,
                                     float& o0, float& o1, float& o2) {
    float s1 = (z0 + z1) + z2;
    float s2 = fmaf(z0, z0, fmaf(z1, z1, z2 * z2));
    float mu = s1 * (1.0f / 3.0f);
    float vpe = fmaf(s2, (1.0f / 3.0f), fmaf(-mu, mu, 1e-5f));
    float rstd = __builtin_amdgcn_rsqf(vpe);
    o0 = fmaf(z0 - mu, rstd * w0, b0);
    o1 = fmaf(z1 - mu, rstd * w1, b1);
    o2 = fmaf(z2 - mu, rstd * w2, b2);
}

__global__ __launch_bounds__(64, 1) void dec_kernel(
    const float* __restrict__ mem,
    const float* __restrict__ sa_qkv_w, const float* __restrict__ sa_qkv_b,
    const float* __restrict__ sa_out_w, const float* __restrict__ sa_out_b,
    const float* __restrict__ gln1_w, const float* __restrict__ gln1_b,
    const float* __restrict__ ca_qkv_w, const float* __restrict__ ca_qkv_b,
    const float* __restrict__ ca_out_w, const float* __restrict__ ca_out_b,
    const float* __restrict__ gln2_w, const float* __restrict__ gln2_b,
    const float* __restrict__ l1_w, const float* __restrict__ l1_b,
    const float* __restrict__ l2_w, const float* __restrict__ l2_b,
    const float* __restrict__ gln3_w, const float* __restrict__ gln3_b,
    float* __restrict__ out)
{
    const int b = blockIdx.x;
    const int lane = threadIdx.x;
    const float LOG2E = 1.4426950408889634f;
    const float rs3 = 0.5773502691896258f;
    const float QS = rs3 * LOG2E;

    // ---- LDS tail, 72-slot rows (16B-aligned):
    // g1: 0-2 Bso | 3-5 N1w | 6-8 N1b | 9-17 Wcq | 18-20 Bcq | 21-23 Bco |
    //     24-26 N2w | 27-29 N2b | 30-31 pad
    // g2: 32-43 F1w | 44-47 F1b | 48-59 F2w | 60-62 F2b | 63-65 N3w |
    //     66-68 N3b | 69-71 pad
    __shared__ __align__(16) float fst[NL_][72];
    for (int t = lane; t < NL_ * 72; t += 64) {
        int l = t / 72, s = t % 72;
        float v = 0.f;
        if      (s < 3)  v = sa_out_b[l * 3 + s];
        else if (s < 6)  v = gln1_w[l * 3 + (s - 3)];
        else if (s < 9)  v = gln1_b[l * 3 + (s - 6)];
        else if (s < 18) v = ca_qkv_w[l * 27 + (s - 9)];
        else if (s < 21) v = ca_qkv_b[l * 9 + (s - 18)];
        else if (s < 24) v = ca_out_b[l * 3 + (s - 21)];
        else if (s < 27) v = gln2_w[l * 3 + (s - 24)];
        else if (s < 30) v = gln2_b[l * 3 + (s - 27)];
        else if (s < 32) v = 0.f;
        else if (s < 44) v = l1_w[l * 12 + (s - 32)];
        else if (s < 48) v = l1_b[l * 4 + (s - 44)];
        else if (s < 60) v = l2_w[l * 12 + (s - 48)];
        else if (s < 63) v = l2_b[l * 3 + (s - 60)];
        else if (s < 66) v = gln3_w[l * 3 + (s - 63)];
        else if (s < 69) v = gln3_b[l * 3 + (s - 66)];
        fst[l][s] = v;
    }
    __syncthreads();

    // ---- pinned SA-path weights (144)
    float Wqp[NL_][3][3], Bqp[NL_][3];
    float Wk [NL_][3][3], Bk [NL_][3];
    float WVp[NL_][3][3], bvp[NL_][3];

    #pragma unroll
    for (int l = 0; l < NL_; ++l) {
        #pragma unroll
        for (int r = 0; r < 3; ++r) {
            Bqp[l][r] = sa_qkv_b[l * 9 + r] * QS;
            Bk [l][r] = sa_qkv_b[l * 9 + 3 + r];
            #pragma unroll
            for (int c = 0; c < 3; ++c) {
                Wqp[l][r][c] = sa_qkv_w[l * 27 + r * 3 + c] * QS;
                Wk [l][r][c] = sa_qkv_w[l * 27 + (3 + r) * 3 + c];
            }
            float a0 = 0.f, a1 = 0.f, a2 = 0.f, ab = 0.f;
            #pragma unroll
            for (int t = 0; t < 3; ++t) {
                float wso = sa_out_w[l * 9 + r * 3 + t];
                a0 += wso * sa_qkv_w[l * 27 + (6 + t) * 3 + 0];
                a1 += wso * sa_qkv_w[l * 27 + (6 + t) * 3 + 1];
                a2 += wso * sa_qkv_w[l * 27 + (6 + t) * 3 + 2];
                ab += wso * sa_qkv_b[l * 9 + 6 + t];
            }
            WVp[l][r][0] = a0; WVp[l][r][1] = a1; WVp[l][r][2] = a2;
            bvp[l][r] = ab;
        }
    }

    // ---- per-lane cross-attn caches: ck scaled by QS, cv' = Wco*cv
    float m0 = mem[(b * S_ + lane) * DD_ + 0];
    float m1 = mem[(b * S_ + lane) * DD_ + 1];
    float m2 = mem[(b * S_ + lane) * DD_ + 2];

    float ck[NL_][3], cvp[NL_][3];
    #pragma unroll
    for (int l = 0; l < NL_; ++l) {
        float cvt[3];
        #pragma unroll
        for (int t = 0; t < 3; ++t) {
            cvt[t] = ca_qkv_w[l * 27 + (6 + t) * 3 + 0] * m0 +
                     ca_qkv_w[l * 27 + (6 + t) * 3 + 1] * m1 +
                     ca_qkv_w[l * 27 + (6 + t) * 3 + 2] * m2 + ca_qkv_b[l * 9 + 6 + t];
        }
        #pragma unroll
        for (int r = 0; r < 3; ++r) {
            float kk = ca_qkv_w[l * 27 + (3 + r) * 3 + 0] * m0 +
                       ca_qkv_w[l * 27 + (3 + r) * 3 + 1] * m1 +
                       ca_qkv_w[l * 27 + (3 + r) * 3 + 2] * m2 + ca_qkv_b[l * 9 + 3 + r];
            ck[l][r] = kk * QS;
            cvp[l][r] = ca_out_w[l * 9 + r * 3 + 0] * cvt[0] +
                        ca_out_w[l * 9 + r * 3 + 1] * cvt[1] +
                        ca_out_w[l * 9 + r * 3 + 2] * cvt[2];
        }
    }

    #pragma unroll
    for (int l = 0; l < NL_; ++l) {
        #pragma unroll
        for (int r = 0; r < 3; ++r) {
            PIN(Bqp[l][r]); PIN(Bk[l][r]); PIN(bvp[l][r]);
            PIN(ck[l][r]); PIN(cvp[l][r]);
            #pragma unroll
            for (int c = 0; c < 3; ++c) {
                PIN(Wqp[l][r][c]); PIN(Wk[l][r][c]); PIN(WVp[l][r][c]);
            }
        }
    }

    float sk[NL_][3] = {{0.f}}, sv[NL_][3] = {{0.f}};

    if (lane < 3) out[(b * S_ + 0) * 5 + lane] = 0.f;

    float y0 = 0.f, y1 = 0.f, y2 = 0.f;

    for (int i = 0; i < S_ - 1; ++i) {
        float msa = (lane <= i) ? 0.f : -1.0e30f;
        #pragma unroll
        for (int l = 0; l < NL_; ++l) {
            // ---- g1: 8 float4 at layer top (first use ~250cy downstream)
            float wa[32];
            {
                const float4* fp = (const float4*)fst[l];
                #pragma unroll
                for (int k = 0; k < 8; ++k) {
                    float4 t4 = fp[k];
                    wa[4 * k + 0] = t4.x; wa[4 * k + 1] = t4.y;
                    wa[4 * k + 2] = t4.z; wa[4 * k + 3] = t4.w;
                }
            }

            // ---- causal self-attention (q pre-scaled; v' = Wso*v)
            float q0 = fmaf(Wqp[l][0][0], y0, fmaf(Wqp[l][0][1], y1, fmaf(Wqp[l][0][2], y2, Bqp[l][0])));
            float q1 = fmaf(Wqp[l][1][0], y0, fmaf(Wqp[l][1][1], y1, fmaf(Wqp[l][1][2], y2, Bqp[l][1])));
            float q2 = fmaf(Wqp[l][2][0], y0, fmaf(Wqp[l][2][1], y1, fmaf(Wqp[l][2][2], y2, Bqp[l][2])));
            float k0 = fmaf(Wk[l][0][0], y0, fmaf(Wk[l][0][1], y1, fmaf(Wk[l][0][2], y2, Bk[l][0])));
            float k1 = fmaf(Wk[l][1][0], y0, fmaf(Wk[l][1][1], y1, fmaf(Wk[l][1][2], y2, Bk[l][1])));
            float k2 = fmaf(Wk[l][2][0], y0, fmaf(Wk[l][2][1], y1, fmaf(Wk[l][2][2], y2, Bk[l][2])));
            float v0 = fmaf(WVp[l][0][0], y0, fmaf(WVp[l][0][1], y1, fmaf(WVp[l][0][2], y2, bvp[l][0])));
            float v1 = fmaf(WVp[l][1][0], y0, fmaf(WVp[l][1][1], y1, fmaf(WVp[l][1][2], y2, bvp[l][1])));
            float v2 = fmaf(WVp[l][2][0], y0, fmaf(WVp[l][2][1], y1, fmaf(WVp[l][2][2], y2, bvp[l][2])));
            if (lane == i) {
                sk[l][0] = k0; sk[l][1] = k1; sk[l][2] = k2;
                sv[l][0] = v0; sv[l][1] = v1; sv[l][2] = v2;
            }
            float sc = fmaf(q0, sk[l][0], fmaf(q1, sk[l][1], fmaf(q2, sk[l][2], msa)));
            float e = __builtin_amdgcn_exp2f(sc);

            // ---- g2: 10 float4 issued under the SA DPP chains
            float wb[40];
            {
                const float4* fp = (const float4*)&fst[l][32];
                #pragma unroll
                for (int k = 0; k < 10; ++k) {
                    float4 t4 = fp[k];
                    wb[4 * k + 0] = t4.x; wb[4 * k + 1] = t4.y;
                    wb[4 * k + 2] = t4.z; wb[4 * k + 3] = t4.w;
                }
            }

            float es  = bcast63(wave_sum_l63(e));
            float ev0 = bcast63(wave_sum_l63(e * sv[l][0]));
            float ev1 = bcast63(wave_sum_l63(e * sv[l][1]));
            float ev2 = bcast63(wave_sum_l63(e * sv[l][2]));
            float t0 = y0 + wa[0], t1 = y1 + wa[1], t2 = y2 + wa[2];
            float z0 = fmaf(t0, es, ev0);
            float z1 = fmaf(t1, es, ev1);
            float z2 = fmaf(t2, es, ev2);
            ln3e(z0, z1, z2, wa[3], wa[4], wa[5], wa[6], wa[7], wa[8],
                 y0, y1, y2);

            // ---- cross-attention (Wcq/Bcq from wa; scale folded into ck)
            float p0 = fmaf(wa[9],  y0, fmaf(wa[10], y1, fmaf(wa[11], y2, wa[18])));
            float p1 = fmaf(wa[12], y0, fmaf(wa[13], y1, fmaf(wa[14], y2, wa[19])));
            float p2 = fmaf(wa[15], y0, fmaf(wa[16], y1, fmaf(wa[17], y2, wa[20])));
            float sc2 = fmaf(p0, ck[l][0], fmaf(p1, ck[l][1], p2 * ck[l][2]));
            float e2 = __builtin_amdgcn_exp2f(sc2);
            float cs  = bcast63(wave_sum_l63(e2));
            float cw0 = bcast63(wave_sum_l63(e2 * cvp[l][0]));
            float cw1 = bcast63(wave_sum_l63(e2 * cvp[l][1]));
            float cw2 = bcast63(wave_sum_l63(e2 * cvp[l][2]));
            float u0 = y0 + wa[21], u1 = y1 + wa[22], u2 = y2 + wa[23];
            z0 = fmaf(u0, cs, cw0);
            z1 = fmaf(u1, cs, cw1);
            z2 = fmaf(u2, cs, cw2);
            ln3e(z0, z1, z2, wa[24], wa[25], wa[26], wa[27], wa[28], wa[29],
                 y0, y1, y2);

            // ---- feed-forward 3 -> 4 -> 3 (relu) from wb
            float h0 = fmaxf(fmaf(wb[0], y0, fmaf(wb[1],  y1, fmaf(wb[2],  y2, wb[12]))), 0.f);
            float h1 = fmaxf(fmaf(wb[3], y0, fmaf(wb[4],  y1, fmaf(wb[5],  y2, wb[13]))), 0.f);
            float h2 = fmaxf(fmaf(wb[6], y0, fmaf(wb[7],  y1, fmaf(wb[8],  y2, wb[14]))), 0.f);
            float h3 = fmaxf(fmaf(wb[9], y0, fmaf(wb[10], y1, fmaf(wb[11], y2, wb[15]))), 0.f);
            float f0 = fmaf(wb[16], h0, fmaf(wb[17], h1, fmaf(wb[18], h2, fmaf(wb[19], h3, wb[28]))));
            float f1 = fmaf(wb[20], h0, fmaf(wb[21], h1, fmaf(wb[22], h2, fmaf(wb[23], h3, wb[29]))));
            float f2 = fmaf(wb[24], h0, fmaf(wb[25], h1, fmaf(wb[26], h2, fmaf(wb[27], h3, wb[30]))));
            ln3e(y0 + f0, y1 + f1, y2 + f2, wb[31], wb[32], wb[33],
                 wb[34], wb[35], wb[36], y0, y1, y2);
        }
        if (lane == 0) {
            out[(b * S_ + i + 1) * 5 + 0] = y0;
            out[(b * S_ + i + 1) * 5 + 1] = y1;
            out[(b * S_ + i + 1) * 5 + 2] = y2;
        }
    }
}

// ---------------------------------------------------------------------------
extern "C" void kernel_launch(void* const* d_in, const int* in_sizes, int n_in,
                              void* d_out, int out_size, void* d_ws, size_t ws_size,
                              hipStream_t stream) {
    const float* src  = (const float*)d_in[0];
    const float* wemb = (const float*)d_in[1];
    const float* semb = (const float*)d_in[2];

    float* mem = (float*)d_ws;           // [B,S,3] scratch
    float* out = (float*)d_out;          // [B,S,5]

    enc_kernel<<<B_, 512, 0, stream>>>(
        src, wemb, semb,
        (const float*)d_in[3],  (const float*)d_in[4],
        (const float*)d_in[5],  (const float*)d_in[6],
        (const float*)d_in[7],  (const float*)d_in[8],
        (const float*)d_in[9],  (const float*)d_in[10],
        (const float*)d_in[11], (const float*)d_in[12],
        (const float*)d_in[13], (const float*)d_in[14],
        (const float*)d_in[15], (const float*)d_in[16],
        (const float*)d_in[17], (const float*)d_in[18],
        mem, out);

    dec_kernel<<<B_, 64, 0, stream>>>(
        mem,
        (const float*)d_in[19], (const float*)d_in[20],
        (const float*)d_in[21], (const float*)d_in[22],
        (const float*)d_in[23], (const float*)d_in[24],
        (const float*)d_in[25], (const float*)d_in[26],
        (const float*)d_in[27], (const float*)d_in[28],
        (const float*)d_in[29], (const float*)d_in[30],
        (const float*)d_in[31], (const float*)d_in[32],
        (const float*)d_in[33], (const float*)d_in[34],
        (const float*)d_in[35], (const float*)d_in[36],
        out);
}

// Round 9
// 348.637 us; speedup vs baseline: 1.1429x; 1.0513x over previous
//
#include <hip/hip_runtime.h>
#include <math.h>

#define B_ 64
#define S_ 64
#define U_ 16
#define EMB_ 10
#define D_ 34
#define DD_ 3
#define FF_ 4
#define NL_ 4

// ---------------------------------------------------------------------------
// Kernel A: encoder (R8 version, unchanged — measured win).
// ---------------------------------------------------------------------------
__global__ __launch_bounds__(512) void enc_kernel(
    const float* __restrict__ src, const float* __restrict__ wemb,
    const float* __restrict__ semb,
    const float* __restrict__ qkv_w, const float* __restrict__ qkv_b,
    const float* __restrict__ out_w, const float* __restrict__ out_b,
    const float* __restrict__ ln1_w, const float* __restrict__ ln1_b,
    const float* __restrict__ lin1_w, const float* __restrict__ lin1_b,
    const float* __restrict__ lin2_w, const float* __restrict__ lin2_b,
    const float* __restrict__ ln2_w, const float* __restrict__ ln2_b,
    const float* __restrict__ norm_w, const float* __restrict__ norm_b,
    const float* __restrict__ eo_w, const float* __restrict__ eo_b,
    float* __restrict__ mem, float* __restrict__ out)
{
    const int b = blockIdx.x;
    const int tid = threadIdx.x;
    const int wv_ = tid >> 6;
    const int lane = tid & 63;

    __shared__ float xs[S_][D_ + 1];
    __shared__ float tmp[S_][D_ + 1];
    __shared__ float att[S_][D_ + 1];
    __shared__ __align__(16) float qsh[2][S_][21];
    __shared__ __align__(16) float ksh[2][S_][20];
    __shared__ __align__(16) float vsh[2][S_][20];
    __shared__ float ffh[S_][5];
    __shared__ float pacc[4][128][19];

    const float negln = -logf(10000.0f) / (float)D_;
    #pragma unroll
    for (int rep = 0; rep < 5; ++rep) {
        int idx = tid + rep * 512;
        if (idx < S_ * D_) {
            int pos = idx / D_, d = idx % D_;
            float v;
            if (d < U_ - 2) {
                v = src[(b * S_ + pos) * U_ + d];
            } else if (d < U_ - 2 + EMB_) {
                int wi = (int)src[(b * S_ + pos) * U_ + (U_ - 2)];
                v = wemb[wi * EMB_ + (d - (U_ - 2))];
            } else {
                int si = (int)src[(b * S_ + pos) * U_ + (U_ - 1)];
                v = semb[si * EMB_ + (d - (U_ - 2 + EMB_))];
            }
            int k = d >> 1;
            float div = __expf((float)(2 * k) * negln);
            float ang = (float)b * div;
            v += (d & 1) ? __cosf(ang) : __sinf(ang);
            xs[pos][d] = v;
        }
    }
    __syncthreads();

    const float rs17 = 0.24253562503633297f;

    for (int l = 0; l < NL_; ++l) {
        const float* Wq = qkv_w + l * 3 * D_ * D_;
        const float* Bq = qkv_b + l * 3 * D_;

        {
            float xr[D_];
            #pragma unroll
            for (int d = 0; d < D_; ++d) xr[d] = xs[lane][d];
            for (int rb = 0; rb < 13; ++rb) {
                int r = wv_ + (rb << 3);
                if (r < 3 * D_) {
                    int ru = __builtin_amdgcn_readfirstlane(r);
                    const float* wrow = Wq + ru * D_;
                    float aE = Bq[ru], aO = 0.f;
                    #pragma unroll
                    for (int d = 0; d < D_; d += 2) {
                        aE = fmaf(xr[d], wrow[d], aE);
                        aO = fmaf(xr[d + 1], wrow[d + 1], aO);
                    }
                    float acc = aE + aO;
                    if (ru < D_)          { int h = (ru >= 17), dd = ru - h * 17; qsh[h][lane][dd] = acc; }
                    else if (ru < 2 * D_) { int rr = ru - D_;     int h = (rr >= 17), dd = rr - h * 17; ksh[h][lane][dd] = acc; }
                    else                  { int rr = ru - 2 * D_; int h = (rr >= 17), dd = rr - h * 17; vsh[h][lane][dd] = acc; }
                }
            }
        }
        __syncthreads();

        {
            int c = tid >> 7, hq = tid & 127;
            int h = hq >> 6, qi = hq & 63;
            float qv[17], acc[17];
            #pragma unroll
            for (int d = 0; d < 17; ++d) { qv[d] = qsh[h][qi][d]; acc[d] = 0.f; }
            float ssum = 0.f;
            int j0 = c * 16;
            for (int jj = 0; jj < 16; ++jj) {
                int j = j0 + jj;
                const float4* kr = (const float4*)ksh[h][j];
                const float4* vr = (const float4*)vsh[h][j];
                float4 k0 = kr[0], k1 = kr[1], k2 = kr[2], k3 = kr[3];
                float  k16 = ksh[h][j][16];
                float4 v0 = vr[0], v1 = vr[1], v2 = vr[2], v3 = vr[3];
                float  v16 = vsh[h][j][16];
                float sE = qv[0]*k0.x + qv[2]*k0.z + qv[4]*k1.x + qv[6]*k1.z +
                           qv[8]*k2.x + qv[10]*k2.z + qv[12]*k3.x + qv[14]*k3.z;
                float sO = qv[1]*k0.y + qv[3]*k0.w + qv[5]*k1.y + qv[7]*k1.w +
                           qv[9]*k2.y + qv[11]*k2.w + qv[13]*k3.y + qv[15]*k3.w;
                float sc = sE + sO + qv[16]*k16;
                float e = __expf(sc * rs17);
                ssum += e;
                acc[0] += e*v0.x;  acc[1] += e*v0.y;  acc[2] += e*v0.z;  acc[3] += e*v0.w;
                acc[4] += e*v1.x;  acc[5] += e*v1.y;  acc[6] += e*v1.z;  acc[7] += e*v1.w;
                acc[8] += e*v2.x;  acc[9] += e*v2.y;  acc[10] += e*v2.z; acc[11] += e*v2.w;
                acc[12] += e*v3.x; acc[13] += e*v3.y; acc[14] += e*v3.z; acc[15] += e*v3.w;
                acc[16] += e*v16;
            }
            #pragma unroll
            for (int d = 0; d < 17; ++d) pacc[c][hq][d] = acc[d];
            pacc[c][hq][17] = ssum;
        }
        __syncthreads();

        if (tid < 128) {
            int h = tid >> 6, qi = tid & 63;
            int off = h * 17;
            float ssum = pacc[0][tid][17] + pacc[1][tid][17] +
                         pacc[2][tid][17] + pacc[3][tid][17];
            float inv = 1.f / ssum;
            #pragma unroll
            for (int d = 0; d < 17; ++d)
                att[qi][off + d] = (pacc[0][tid][d] + pacc[1][tid][d] +
                                    pacc[2][tid][d] + pacc[3][tid][d]) * inv;
        }
        __syncthreads();

        {
            float ar[D_];
            #pragma unroll
            for (int e = 0; e < D_; ++e) ar[e] = att[lane][e];
            const float* Wo = out_w + l * D_ * D_;
            const float* Bo = out_b + l * D_;
            for (int rb = 0; rb < 5; ++rb) {
                int d = wv_ + (rb << 3);
                if (d < D_) {
                    int du = __builtin_amdgcn_readfirstlane(d);
                    const float* wrow = Wo + du * D_;
                    float aE = Bo[du], aO = 0.f;
                    #pragma unroll
                    for (int e = 0; e < D_; e += 2) {
                        aE = fmaf(ar[e], wrow[e], aE);
                        aO = fmaf(ar[e + 1], wrow[e + 1], aO);
                    }
                    tmp[lane][du] = xs[lane][du] + aE + aO;
                }
            }
        }
        __syncthreads();

        if (tid < S_) {
            int row = tid;
            float sA = 0.f, sB = 0.f;
            #pragma unroll
            for (int d = 0; d < D_; d += 2) { sA += tmp[row][d]; sB += tmp[row][d + 1]; }
            float mu = (sA + sB) * (1.0f / D_);
            float vA = 0.f, vB = 0.f;
            #pragma unroll
            for (int d = 0; d < D_; d += 2) {
                float t0 = tmp[row][d] - mu;     vA += t0 * t0;
                float t1 = tmp[row][d + 1] - mu; vB += t1 * t1;
            }
            float rstd = rsqrtf((vA + vB) * (1.0f / D_) + 1e-5f);
            #pragma unroll
            for (int d = 0; d < D_; ++d)
                xs[row][d] = (tmp[row][d] - mu) * rstd * ln1_w[l * D_ + d] + ln1_b[l * D_ + d];
        }
        __syncthreads();

        if (wv_ < 4) {
            int fu = __builtin_amdgcn_readfirstlane(wv_);
            const float* wrow = lin1_w + l * FF_ * D_ + fu * D_;
            float aE = lin1_b[l * FF_ + fu], aO = 0.f;
            #pragma unroll
            for (int d = 0; d < D_; d += 2) {
                aE = fmaf(xs[lane][d], wrow[d], aE);
                aO = fmaf(xs[lane][d + 1], wrow[d + 1], aO);
            }
            ffh[lane][fu] = fmaxf(aE + aO, 0.f);
        }
        __syncthreads();

        {
            float h0 = ffh[lane][0], h1 = ffh[lane][1],
                  h2 = ffh[lane][2], h3 = ffh[lane][3];
            const float* W2 = lin2_w + l * D_ * FF_;
            const float* B2 = lin2_b + l * D_;
            for (int rb = 0; rb < 5; ++rb) {
                int d = wv_ + (rb << 3);
                if (d < D_) {
                    int du = __builtin_amdgcn_readfirstlane(d);
                    const float* wrow = W2 + du * FF_;
                    float acc = fmaf(h0, wrow[0], fmaf(h1, wrow[1],
                                fmaf(h2, wrow[2], fmaf(h3, wrow[3], B2[du]))));
                    tmp[lane][du] = xs[lane][du] + acc;
                }
            }
        }
        __syncthreads();

        if (tid < S_) {
            int row = tid;
            float sA = 0.f, sB = 0.f;
            #pragma unroll
            for (int d = 0; d < D_; d += 2) { sA += tmp[row][d]; sB += tmp[row][d + 1]; }
            float mu = (sA + sB) * (1.0f / D_);
            float vA = 0.f, vB = 0.f;
            #pragma unroll
            for (int d = 0; d < D_; d += 2) {
                float t0 = tmp[row][d] - mu;     vA += t0 * t0;
                float t1 = tmp[row][d + 1] - mu; vB += t1 * t1;
            }
            float rstd = rsqrtf((vA + vB) * (1.0f / D_) + 1e-5f);
            #pragma unroll
            for (int d = 0; d < D_; ++d)
                xs[row][d] = (tmp[row][d] - mu) * rstd * ln2_w[l * D_ + d] + ln2_b[l * D_ + d];
        }
        __syncthreads();
    }

    if (tid < S_) {
        int row = tid;
        float sA = 0.f, sB = 0.f;
        #pragma unroll
        for (int d = 0; d < D_; d += 2) { sA += xs[row][d]; sB += xs[row][d + 1]; }
        float mu = (sA + sB) * (1.0f / D_);
        float vA = 0.f, vB = 0.f;
        #pragma unroll
        for (int d = 0; d < D_; d += 2) {
            float t0 = xs[row][d] - mu;     vA += t0 * t0;
            float t1 = xs[row][d + 1] - mu; vB += t1 * t1;
        }
        float rstd = rsqrtf((vA + vB) * (1.0f / D_) + 1e-5f);
        #pragma unroll
        for (int d = 0; d < D_; ++d)
            xs[row][d] = (xs[row][d] - mu) * rstd * norm_w[d] + norm_b[d];
    }
    __syncthreads();

    if (wv_ < 3) {
        int ru = __builtin_amdgcn_readfirstlane(wv_);
        const float* wrow = eo_w + ru * D_;
        float aE = eo_b[ru], aO = 0.f;
        #pragma unroll
        for (int d = 0; d < D_; d += 2) {
            aE = fmaf(xs[lane][d], wrow[d], aE);
            aO = fmaf(xs[lane][d + 1], wrow[d + 1], aO);
        }
        mem[(b * S_ + lane) * DD_ + ru] = aE + aO;
    }

    if (tid < S_) {
        out[(b * S_ + tid) * 5 + 3] = src[(b * S_ + tid) * U_ + (U_ - 2)];
        out[(b * S_ + tid) * 5 + 4] = src[(b * S_ + tid) * U_ + (U_ - 1)];
    }
}

// ---------------------------------------------------------------------------
// Kernel B: decoder — EXACT R5 structure (measured 161.6 µs: 336-value pin,
// fst[NL][40] FF-tail with PIN at layer top) + local chain algebra only:
// exp2 with QS=rs3*log2e folded into pinned q/CA-q weights, causal mask as
// fma-accumulator init, ln3e (sum||sumsq) LayerNorm. No structural changes.
// ---------------------------------------------------------------------------
#define PIN(x) asm volatile("" : "+v"(x))

template <int CTRL>
__device__ __forceinline__ float dpp_add(float v) {
    int t = __builtin_amdgcn_update_dpp(0, __float_as_int(v), CTRL, 0xf, 0xf, true);
    return v + __int_as_float(t);
}

__device__ __forceinline__ float wave_sum_l63(float v) {
    v = dpp_add<0x111>(v);
    v = dpp_add<0x112>(v);
    v = dpp_add<0x114>(v);
    v = dpp_add<0x118>(v);
    v = dpp_add<0x142>(v);
    v = dpp_add<0x143>(v);
    return v;
}

__device__ __forceinline__ float bcast63(float v) {
    return __int_as_float(__builtin_amdgcn_readlane(__float_as_int(v), 63));
}

__device__ __forceinline__ void ln3e(float z0, float z1, float z2,
                                     float w0, float w1, float w2,
                                     float b0, float b1, float b2,
                                     float& o0, float& o1, float& o2) {
    float s1 = (z0 + z1) + z2;
    float s2 = fmaf(z0, z0, fmaf(z1, z1, z2 * z2));
    float mu = s1 * (1.0f / 3.0f);
    float vpe = fmaf(s2, (1.0f / 3.0f), fmaf(-mu, mu, 1e-5f));
    float rstd = __builtin_amdgcn_rsqf(vpe);
    o0 = fmaf(z0 - mu, rstd * w0, b0);
    o1 = fmaf(z1 - mu, rstd * w1, b1);
    o2 = fmaf(z2 - mu, rstd * w2, b2);
}

__global__ __launch_bounds__(64, 1) void dec_kernel(
    const float* __restrict__ mem,
    const float* __restrict__ sa_qkv_w, const float* __restrict__ sa_qkv_b,
    const float* __restrict__ sa_out_w, const float* __restrict__ sa_out_b,
    const float* __restrict__ gln1_w, const float* __restrict__ gln1_b,
    const float* __restrict__ ca_qkv_w, const float* __restrict__ ca_qkv_b,
    const float* __restrict__ ca_out_w, const float* __restrict__ ca_out_b,
    const float* __restrict__ gln2_w, const float* __restrict__ gln2_b,
    const float* __restrict__ l1_w, const float* __restrict__ l1_b,
    const float* __restrict__ l2_w, const float* __restrict__ l2_b,
    const float* __restrict__ gln3_w, const float* __restrict__ gln3_b,
    float* __restrict__ out)
{
    const int b = blockIdx.x;
    const int lane = threadIdx.x;
    const float LOG2E = 1.4426950408889634f;
    const float rs3 = 0.5773502691896258f;
    const float QS = rs3 * LOG2E;   // score scale folded into weights, exp->exp2

    // ---- FF-tail weight stage (identical layout to R5): F1w 0..11,
    // F1b 12..15, F2w 16..27, F2b 28..30, N3w 31..33, N3b 34..36
    __shared__ __align__(16) float fst[NL_][40];
    for (int t = lane; t < NL_ * 40; t += 64) {
        int l = t / 40, s = t % 40;
        float v = 0.f;
        if      (s < 12) v = l1_w[l * 12 + s];
        else if (s < 16) v = l1_b[l * 4 + (s - 12)];
        else if (s < 28) v = l2_w[l * 12 + (s - 16)];
        else if (s < 31) v = l2_b[l * 3 + (s - 28)];
        else if (s < 34) v = gln3_w[l * 3 + (s - 31)];
        else if (s < 37) v = gln3_b[l * 3 + (s - 34)];
        fst[l][s] = v;
    }
    __syncthreads();

    // ---- persistent pinned weights (R5 set, q rows scaled by QS)
    float Wsq[NL_][9][3], Bsq[NL_][9];
    float Wso[NL_][3][3], Bso[NL_][3];
    float N1w[NL_][3], N1b[NL_][3];
    float Wcq[NL_][3][3], Bcq[NL_][3];
    float Wco[NL_][3][3], Bco[NL_][3];
    float N2w[NL_][3], N2b[NL_][3];

    #pragma unroll
    for (int l = 0; l < NL_; ++l) {
        #pragma unroll
        for (int r = 0; r < 9; ++r) {
            float sc = (r < 3) ? QS : 1.0f;   // fold rs3*log2e into q rows
            Bsq[l][r] = sa_qkv_b[l * 9 + r] * sc;
            #pragma unroll
            for (int c = 0; c < 3; ++c) Wsq[l][r][c] = sa_qkv_w[l * 27 + r * 3 + c] * sc;
        }
        #pragma unroll
        for (int r = 0; r < 3; ++r) {
            Bso[l][r] = sa_out_b[l * 3 + r];
            Bcq[l][r] = ca_qkv_b[l * 9 + r] * QS;
            Bco[l][r] = ca_out_b[l * 3 + r];
            N1w[l][r] = gln1_w[l * 3 + r];  N1b[l][r] = gln1_b[l * 3 + r];
            N2w[l][r] = gln2_w[l * 3 + r];  N2b[l][r] = gln2_b[l * 3 + r];
            #pragma unroll
            for (int c = 0; c < 3; ++c) {
                Wso[l][r][c] = sa_out_w[l * 9 + r * 3 + c];
                Wcq[l][r][c] = ca_qkv_w[l * 27 + r * 3 + c] * QS;
                Wco[l][r][c] = ca_out_w[l * 9 + r * 3 + c];
            }
        }
    }

    // ---- cross-attn K/V per lane (memory position = lane)
    float m0 = mem[(b * S_ + lane) * DD_ + 0];
    float m1 = mem[(b * S_ + lane) * DD_ + 1];
    float m2 = mem[(b * S_ + lane) * DD_ + 2];

    float ck[NL_][3], cv[NL_][3];
    #pragma unroll
    for (int l = 0; l < NL_; ++l) {
        #pragma unroll
        for (int r = 0; r < 3; ++r) {
            ck[l][r] = ca_qkv_w[l * 27 + (3 + r) * 3 + 0] * m0 +
                       ca_qkv_w[l * 27 + (3 + r) * 3 + 1] * m1 +
                       ca_qkv_w[l * 27 + (3 + r) * 3 + 2] * m2 + ca_qkv_b[l * 9 + 3 + r];
            cv[l][r] = ca_qkv_w[l * 27 + (6 + r) * 3 + 0] * m0 +
                       ca_qkv_w[l * 27 + (6 + r) * 3 + 1] * m1 +
                       ca_qkv_w[l * 27 + (6 + r) * 3 + 2] * m2 + ca_qkv_b[l * 9 + 6 + r];
        }
    }

    // ---- pin the chain-critical set (R5 set)
    #pragma unroll
    for (int l = 0; l < NL_; ++l) {
        #pragma unroll
        for (int r = 0; r < 9; ++r) {
            PIN(Bsq[l][r]);
            #pragma unroll
            for (int c = 0; c < 3; ++c) PIN(Wsq[l][r][c]);
        }
        #pragma unroll
        for (int r = 0; r < 3; ++r) {
            PIN(Bso[l][r]); PIN(Bcq[l][r]); PIN(Bco[l][r]);
            PIN(N1w[l][r]); PIN(N1b[l][r]); PIN(N2w[l][r]); PIN(N2b[l][r]);
            #pragma unroll
            for (int c = 0; c < 3; ++c) { PIN(Wso[l][r][c]); PIN(Wcq[l][r][c]); PIN(Wco[l][r][c]); }
        }
    }

    // self-attn KV cache: lane j owns position j
    float sk[NL_][3] = {{0.f}}, sv[NL_][3] = {{0.f}};

    if (lane < 3) out[(b * S_ + 0) * 5 + lane] = 0.f;

    float y0 = 0.f, y1 = 0.f, y2 = 0.f;

    for (int i = 0; i < S_ - 1; ++i) {
        float msa = (lane <= i) ? 0.f : -1.0e30f;   // causal mask, once/step
        #pragma unroll
        for (int l = 0; l < NL_; ++l) {
            // ---- FF-tail weights: LDS reads at layer top, PINned (R5 scheme)
            float wv[40];
            {
                const float4* fp = (const float4*)fst[l];
                #pragma unroll
                for (int k = 0; k < 10; ++k) {
                    float4 t4 = fp[k];
                    wv[4 * k + 0] = t4.x; wv[4 * k + 1] = t4.y;
                    wv[4 * k + 2] = t4.z; wv[4 * k + 3] = t4.w;
                }
                #pragma unroll
                for (int k = 0; k < 37; ++k) PIN(wv[k]);
            }

            // ---- causal self-attention (q pre-scaled by QS; mask in fma)
            float q[3], kn[3], vn[3];
            #pragma unroll
            for (int r = 0; r < 3; ++r) {
                q[r]  = fmaf(Wsq[l][r][0], y0, fmaf(Wsq[l][r][1], y1, fmaf(Wsq[l][r][2], y2, Bsq[l][r])));
                kn[r] = fmaf(Wsq[l][3 + r][0], y0, fmaf(Wsq[l][3 + r][1], y1, fmaf(Wsq[l][3 + r][2], y2, Bsq[l][3 + r])));
                vn[r] = fmaf(Wsq[l][6 + r][0], y0, fmaf(Wsq[l][6 + r][1], y1, fmaf(Wsq[l][6 + r][2], y2, Bsq[l][6 + r])));
            }
            if (lane == i) {
                #pragma unroll
                for (int r = 0; r < 3; ++r) { sk[l][r] = kn[r]; sv[l][r] = vn[r]; }
            }
            float sc = fmaf(q[0], sk[l][0], fmaf(q[1], sk[l][1], fmaf(q[2], sk[l][2], msa)));
            float e = __builtin_amdgcn_exp2f(sc);
            float es  = wave_sum_l63(e);
            float ev0 = wave_sum_l63(e * sv[l][0]);
            float ev1 = wave_sum_l63(e * sv[l][1]);
            float ev2 = wave_sum_l63(e * sv[l][2]);
            float inv = __builtin_amdgcn_rcpf(bcast63(es));
            float a0 = bcast63(ev0) * inv, a1 = bcast63(ev1) * inv, a2 = bcast63(ev2) * inv;
            float s0 = fmaf(Wso[l][0][0], a0, fmaf(Wso[l][0][1], a1, fmaf(Wso[l][0][2], a2, Bso[l][0])));
            float s1 = fmaf(Wso[l][1][0], a0, fmaf(Wso[l][1][1], a1, fmaf(Wso[l][1][2], a2, Bso[l][1])));
            float s2 = fmaf(Wso[l][2][0], a0, fmaf(Wso[l][2][1], a1, fmaf(Wso[l][2][2], a2, Bso[l][2])));
            ln3e(y0 + s0, y1 + s1, y2 + s2,
                 N1w[l][0], N1w[l][1], N1w[l][2], N1b[l][0], N1b[l][1], N1b[l][2],
                 y0, y1, y2);

            // ---- cross-attention (p pre-scaled by QS)
            float p0 = fmaf(Wcq[l][0][0], y0, fmaf(Wcq[l][0][1], y1, fmaf(Wcq[l][0][2], y2, Bcq[l][0])));
            float p1 = fmaf(Wcq[l][1][0], y0, fmaf(Wcq[l][1][1], y1, fmaf(Wcq[l][1][2], y2, Bcq[l][1])));
            float p2 = fmaf(Wcq[l][2][0], y0, fmaf(Wcq[l][2][1], y1, fmaf(Wcq[l][2][2], y2, Bcq[l][2])));
            float sc2 = fmaf(p0, ck[l][0], fmaf(p1, ck[l][1], p2 * ck[l][2]));
            float e2 = __builtin_amdgcn_exp2f(sc2);
            float cs  = wave_sum_l63(e2);
            float cw0 = wave_sum_l63(e2 * cv[l][0]);
            float cw1 = wave_sum_l63(e2 * cv[l][1]);
            float cw2 = wave_sum_l63(e2 * cv[l][2]);
            inv = __builtin_amdgcn_rcpf(bcast63(cs));
            a0 = bcast63(cw0) * inv; a1 = bcast63(cw1) * inv; a2 = bcast63(cw2) * inv;
            float c0 = fmaf(Wco[l][0][0], a0, fmaf(Wco[l][0][1], a1, fmaf(Wco[l][0][2], a2, Bco[l][0])));
            float c1 = fmaf(Wco[l][1][0], a0, fmaf(Wco[l][1][1], a1, fmaf(Wco[l][1][2], a2, Bco[l][1])));
            float c2 = fmaf(Wco[l][2][0], a0, fmaf(Wco[l][2][1], a1, fmaf(Wco[l][2][2], a2, Bco[l][2])));
            ln3e(y0 + c0, y1 + c1, y2 + c2,
                 N2w[l][0], N2w[l][1], N2w[l][2], N2b[l][0], N2b[l][1], N2b[l][2],
                 y0, y1, y2);

            // ---- feed-forward 3 -> 4 -> 3 (relu) from LDS-staged wv[]
            float h0 = fmaxf(fmaf(wv[0], y0, fmaf(wv[1],  y1, fmaf(wv[2],  y2, wv[12]))), 0.f);
            float h1 = fmaxf(fmaf(wv[3], y0, fmaf(wv[4],  y1, fmaf(wv[5],  y2, wv[13]))), 0.f);
            float h2 = fmaxf(fmaf(wv[6], y0, fmaf(wv[7],  y1, fmaf(wv[8],  y2, wv[14]))), 0.f);
            float h3 = fmaxf(fmaf(wv[9], y0, fmaf(wv[10], y1, fmaf(wv[11], y2, wv[15]))), 0.f);
            float f0 = fmaf(wv[16], h0, fmaf(wv[17], h1, fmaf(wv[18], h2, fmaf(wv[19], h3, wv[28]))));
            float f1 = fmaf(wv[20], h0, fmaf(wv[21], h1, fmaf(wv[22], h2, fmaf(wv[23], h3, wv[29]))));
            float f2 = fmaf(wv[24], h0, fmaf(wv[25], h1, fmaf(wv[26], h2, fmaf(wv[27], h3, wv[30]))));
            ln3e(y0 + f0, y1 + f1, y2 + f2,
                 wv[31], wv[32], wv[33], wv[34], wv[35], wv[36],
                 y0, y1, y2);
        }
        if (lane == 0) {
            out[(b * S_ + i + 1) * 5 + 0] = y0;
            out[(b * S_ + i + 1) * 5 + 1] = y1;
            out[(b * S_ + i + 1) * 5 + 2] = y2;
        }
    }
}

// ---------------------------------------------------------------------------
extern "C" void kernel_launch(void* const* d_in, const int* in_sizes, int n_in,
                              void* d_out, int out_size, void* d_ws, size_t ws_size,
                              hipStream_t stream) {
    const float* src  = (const float*)d_in[0];
    const float* wemb = (const float*)d_in[1];
    const float* semb = (const float*)d_in[2];

    float* mem = (float*)d_ws;           // [B,S,3] scratch
    float* out = (float*)d_out;          // [B,S,5]

    enc_kernel<<<B_, 512, 0, stream>>>(
        src, wemb, semb,
        (const float*)d_in[3],  (const float*)d_in[4],
        (const float*)d_in[5],  (const float*)d_in[6],
        (const float*)d_in[7],  (const float*)d_in[8],
        (const float*)d_in[9],  (const float*)d_in[10],
        (const float*)d_in[11], (const float*)d_in[12],
        (const float*)d_in[13], (const float*)d_in[14],
        (const float*)d_in[15], (const float*)d_in[16],
        (const float*)d_in[17], (const float*)d_in[18],
        mem, out);

    dec_kernel<<<B_, 64, 0, stream>>>(
        mem,
        (const float*)d_in[19], (const float*)d_in[20],
        (const float*)d_in[21], (const float*)d_in[22],
        (const float*)d_in[23], (const float*)d_in[24],
        (const float*)d_in[25], (const float*)d_in[26],
        (const float*)d_in[27], (const float*)d_in[28],
        (const float*)d_in[29], (const float*)d_in[30],
        (const float*)d_in[31], (const float*)d_in[32],
        (const float*)d_in[33], (const float*)d_in[34],
        (const float*)d_in[35], (const float*)d_in[36],
        out);
}